// Round 3
// baseline (278.747 us; speedup 1.0000x reference)
//
#include <hip/hip_runtime.h>
#include <hip/hip_bf16.h>

#define EMBED 1024
#define NHEADS 16
#define HDIM 64
#define SEQ 2048
#define BATCH 4
#define ROWS (BATCH * SEQ) /* 8192 */

typedef __attribute__((ext_vector_type(8))) short bf16x8;   // 8 bf16 = 4 VGPRs
typedef __attribute__((ext_vector_type(4))) float f32x4;
typedef __attribute__((ext_vector_type(2))) float f32x2;
typedef __attribute__((ext_vector_type(16))) float f32x16;
typedef __attribute__((ext_vector_type(4))) unsigned int u32x4;
typedef __attribute__((ext_vector_type(2))) unsigned int u32x2;
typedef __attribute__((ext_vector_type(2))) int i32x2;
typedef unsigned int u32;

#define SL2E 0.18033688011112042f  /* 0.125 * log2(e) */

__device__ __forceinline__ short f2bf(float f) {            // RTNA fp32->bf16 (2 ops)
    u32 u = __builtin_bit_cast(u32, f) + 0x8000u;
    return (short)(u >> 16);
}

__device__ __forceinline__ u32 pkbf(float a, float b) {     // {bf16(a)|bf16(b)<<16}, 3 ops
    u32 ua = __builtin_bit_cast(u32, a) + 0x8000u;
    u32 ub = __builtin_bit_cast(u32, b) + 0x8000u;
    return __builtin_amdgcn_perm(ua, ub, 0x03020706u);      // v_perm_b32: {a.hi16, b.hi16}
}

__device__ __forceinline__ float fexp2(float x) {
#if __has_builtin(__builtin_amdgcn_exp2f)
    return __builtin_amdgcn_exp2f(x);                       // bare v_exp_f32
#else
    return exp2f(x);
#endif
}

__device__ __forceinline__ void async16(const void* g, void* l) {
    __builtin_amdgcn_global_load_lds((const __attribute__((address_space(1))) u32*)g,
                                     (__attribute__((address_space(3))) u32*)l, 16, 0, 0);
}

// ---------- fp32 -> bf16 elementwise (X) ----------
__global__ __launch_bounds__(256) void convert_f32_bf16(const float* __restrict__ in,
                                                        short* __restrict__ out) {
    int i = (blockIdx.x * 256 + threadIdx.x) * 4;
    float4 v = *(const float4*)&in[i];
    u32x2 o = { pkbf(v.x, v.y), pkbf(v.z, v.w) };
    *(u32x2*)&out[i] = o;
}

// ---------- W[K][N] fp32 -> WT[N][K] bf16; z==0 (Wq) pre-scaled by SL2E ----------
__global__ __launch_bounds__(256) void transpose_w4(const float* __restrict__ W0,
                                                    const float* __restrict__ W1,
                                                    const float* __restrict__ W2,
                                                    const float* __restrict__ W3,
                                                    short* __restrict__ T0,
                                                    short* __restrict__ T1,
                                                    short* __restrict__ T2,
                                                    short* __restrict__ T3) {
    const int z = blockIdx.z;
    const float* W = (z == 0) ? W0 : (z == 1) ? W1 : (z == 2) ? W2 : W3;
    short* WT = (z == 0) ? T0 : (z == 1) ? T1 : (z == 2) ? T2 : T3;
    const float sc = (z == 0) ? SL2E : 1.0f;
    __shared__ float T[64][65];
    const int k0 = blockIdx.y * 64, n0 = blockIdx.x * 64;
    const int rr = threadIdx.x >> 4, cc = (threadIdx.x & 15) * 4;
    #pragma unroll
    for (int p = 0; p < 4; ++p) {
        int r = p * 16 + rr;
        float4 v = *(const float4*)&W[(size_t)(k0 + r) * EMBED + n0 + cc];
        T[r][cc] = v.x * sc; T[r][cc + 1] = v.y * sc; T[r][cc + 2] = v.z * sc; T[r][cc + 3] = v.w * sc;
    }
    __syncthreads();
    #pragma unroll
    for (int p = 0; p < 4; ++p) {
        int r = p * 16 + rr;  // n offset
        u32x2 o = { pkbf(T[cc][r], T[cc + 1][r]), pkbf(T[cc + 2][r], T[cc + 3][r]) };
        *(u32x2*)&WT[(size_t)(n0 + r) * EMBED + k0 + cc] = o;
    }
}

// ============================================================================
// R11 schedule + R12 XCD swizzle: 256x256 8-phase GEMM, register-reuse.
// Quadrant order per K-tile: (0,0) (0,1) (1,1) (1,0); frags persist in regs:
//   aU = current A-half (reloaded ph1/ph3), bE = B-half0 (ph1, reused ph4),
//   bO = B-half1 (ph2, reused ph3).  Phase ds_read counts: 12/4/8/0.
// Stage schedule (1 half-tile per phase), vmcnt(6) = 3 half-tiles in flight.
// ============================================================================
__global__ __launch_bounds__(512, 2) void gemm256(const short* __restrict__ A,
                                                  const short* __restrict__ BT,
                                                  const float* __restrict__ b0,
                                                  const float* __restrict__ b1,
                                                  const float* __restrict__ b2,
                                                  void* __restrict__ C0,
                                                  void* __restrict__ C1,
                                                  void* __restrict__ C2,
                                                  int mode) {
    __shared__ short As[2][16384];   // [buf][256 rows][64 k], 16B chunks XOR-swizzled
    __shared__ short Bs[2][16384];   // [buf][256 cols][64 k]
    const int tid = threadIdx.x;
    const int wid = tid >> 6, lane = tid & 63;
    const int c16 = lane & 15, quad = lane >> 4, sw = c16 & 7;
    const int wm = wid >> 2, wn = wid & 3;            // 2M x 4N wave grid
    // T1: bijective chunked XCD swizzle (nwg % 8 == 0 for both launches)
    const int gx = gridDim.x;
    const int hid = blockIdx.y * gx + blockIdx.x;
    const int cpx = (gx * gridDim.y) >> 3;
    const int tle = (hid & 7) * cpx + (hid >> 3);
    const int bx = tle % gx, by = tle / gx;
    const int rowblk = by * 256, colblk = bx * 256;

    // staging: thread handles 16B chunks c = tid and tid+512 of each half-tile
    // (128 rows x 64 k); read-side swizzle inverse pre-applied to global src.
    const int r0 = tid >> 3;                          // 0..63  (and +64 for j=1)
    const int g0 = (tid & 7) ^ (r0 & 7);
    const short* aS0 = A + (size_t)(rowblk + r0) * EMBED + g0 * 8;
    const short* bS0 = BT + (size_t)(colblk + r0) * EMBED + g0 * 8;

#define STAGE_A(SBUF, H, V) do { \
    const short* _s = aS0 + (size_t)(H) * 131072 + (V) * 64; \
    async16(_s,         &As[SBUF][(H) * 8192 + wid * 512]); \
    async16(_s + 65536, &As[SBUF][(H) * 8192 + wid * 512 + 4096]); \
} while (0)
#define STAGE_B(SBUF, H, V) do { \
    const short* _s = bS0 + (size_t)(H) * 131072 + (V) * 64; \
    async16(_s,         &Bs[SBUF][(H) * 8192 + wid * 512]); \
    async16(_s + 65536, &Bs[SBUF][(H) * 8192 + wid * 512 + 4096]); \
} while (0)

    f32x4 acc[8][4] = {};            // [m = mh*4+fm][n = nh*2+fn], static idx
    bf16x8 aU[4][2], bE[2][2], bO[2][2];

#define LDA(BUF, MH) do { \
    _Pragma("unroll") \
    for (int fm = 0; fm < 4; ++fm) { \
        const int row = (MH) * 128 + wm * 64 + fm * 16 + c16; \
        _Pragma("unroll") \
        for (int ks = 0; ks < 2; ++ks) \
            aU[fm][ks] = *(const bf16x8*)&As[BUF][row * 64 + ((ks * 4 + quad) ^ sw) * 8]; \
    } \
} while (0)
#define LDB(BUF, NH, DST) do { \
    _Pragma("unroll") \
    for (int fn = 0; fn < 2; ++fn) { \
        const int rowb = (NH) * 128 + wn * 32 + fn * 16 + c16; \
        _Pragma("unroll") \
        for (int ks = 0; ks < 2; ++ks) \
            DST[fn][ks] = *(const bf16x8*)&Bs[BUF][rowb * 64 + ((ks * 4 + quad) ^ sw) * 8]; \
    } \
} while (0)
#define MM(MB, NB, BM_) do { \
    _Pragma("unroll") \
    for (int fm = 0; fm < 4; ++fm) \
        _Pragma("unroll") \
        for (int fn = 0; fn < 2; ++fn) \
            _Pragma("unroll") \
            for (int ks = 0; ks < 2; ++ks) \
                acc[(MB) + fm][(NB) + fn] = \
                    __builtin_amdgcn_mfma_f32_16x16x32_bf16(aU[fm][ks], BM_[fn][ks], \
                        acc[(MB) + fm][(NB) + fn], 0, 0, 0); \
} while (0)
#define PH_MID() do { \
    __builtin_amdgcn_s_barrier(); \
    asm volatile("s_waitcnt lgkmcnt(0)" ::: "memory"); \
    __builtin_amdgcn_s_setprio(1); \
} while (0)
#define PH_END(VM) do { \
    __builtin_amdgcn_s_setprio(0); \
    if (VM) asm volatile("s_waitcnt vmcnt(6)" ::: "memory"); \
    __builtin_amdgcn_s_barrier(); \
} while (0)

    // prologue: tile0 complete; tile1 {B0,A0,A1} in flight (3 half-tiles)
    STAGE_B(0, 0, 0); STAGE_A(0, 0, 0); STAGE_A(0, 1, 0); STAGE_B(0, 1, 0);
    STAGE_B(1, 0, 1); STAGE_A(1, 0, 1); STAGE_A(1, 1, 1);
    asm volatile("s_waitcnt vmcnt(6)" ::: "memory");
    __builtin_amdgcn_s_barrier();

    #pragma unroll 1
    for (int it = 0; it < 8; ++it) {
        const int u = 2 * it;
        const int v1 = u + 1, v2 = (u + 2) & 15, v3 = (u + 3) & 15;
        // ---- tile u (buf0) ----
        LDA(0, 0); LDB(0, 0, bE); STAGE_B(1, 1, v1); PH_MID(); MM(0, 0, bE); PH_END(0);
        LDB(0, 1, bO);            STAGE_B(0, 0, v2); PH_MID(); MM(0, 2, bO); PH_END(0);
        LDA(0, 1);                STAGE_A(0, 0, v2); PH_MID(); MM(4, 2, bO); PH_END(0);
        /* no ds_reads */         STAGE_A(0, 1, v2); PH_MID(); MM(4, 0, bE); PH_END(1);
        // ---- tile u+1 (buf1) ----
        LDA(1, 0); LDB(1, 0, bE); STAGE_B(0, 1, v2); PH_MID(); MM(0, 0, bE); PH_END(0);
        LDB(1, 1, bO);            STAGE_B(1, 0, v3); PH_MID(); MM(0, 2, bO); PH_END(0);
        LDA(1, 1);                STAGE_A(1, 0, v3); PH_MID(); MM(4, 2, bO); PH_END(0);
        /* no ds_reads */         STAGE_A(1, 1, v3); PH_MID(); MM(4, 0, bE); PH_END(1);
    }

    // drain dangling prefetches before the wave retires
    asm volatile("s_waitcnt vmcnt(0)" ::: "memory");

    // epilogue: C/D frag layout col = lane&15, row = quad*4 + reg
    const int rb0 = rowblk + wm * 64 + quad * 4;
    const int cb0 = wn * 32 + c16;
    if (mode == 0) {
        const int z = colblk >> 10;               // block's 256 cols lie in one of Q/K/V
        const int cm = colblk & 1023;
        const float* bias = (z == 0) ? b0 : (z == 1) ? b1 : b2;
        if (z == 2) {
            short* Vt = (short*)C2;               // Vt[bh][d][s], 4 consecutive s per frag
            #pragma unroll
            for (int m = 0; m < 8; ++m) {
                const int row = rb0 + (m >> 2) * 128 + (m & 3) * 16;
                const int b = row >> 11, s = row & 2047;
                #pragma unroll
                for (int n = 0; n < 4; ++n) {
                    const int cv = cm + cb0 + (n >> 1) * 128 + (n & 1) * 16;
                    const int head = cv >> 6, d = cv & 63;
                    const float bv = bias[cv];
                    u32x2 o = { pkbf(acc[m][n][0] + bv, acc[m][n][1] + bv),
                                pkbf(acc[m][n][2] + bv, acc[m][n][3] + bv) };
                    *(u32x2*)&Vt[((size_t)(b * NHEADS + head) * HDIM + d) * SEQ + s] = o;
                }
            }
        } else {
            short* Cq = (short*)((z == 0) ? C0 : C1);
            const float bsc = (z == 0) ? SL2E : 1.0f;
            #pragma unroll
            for (int m = 0; m < 8; ++m) {
                const int row = rb0 + (m >> 2) * 128 + (m & 3) * 16;
                #pragma unroll
                for (int n = 0; n < 4; ++n) {
                    const int col = cm + cb0 + (n >> 1) * 128 + (n & 1) * 16;
                    const float bv = bias[col] * bsc;
                    #pragma unroll
                    for (int r = 0; r < 4; ++r)
                        Cq[(size_t)(row + r) * EMBED + col] = f2bf(acc[m][n][r] + bv);
                }
            }
        }
    } else {
        float* Co = (float*)C0;
        #pragma unroll
        for (int m = 0; m < 8; ++m) {
            const int row = rb0 + (m >> 2) * 128 + (m & 3) * 16;
            #pragma unroll
            for (int n = 0; n < 4; ++n) {
                const int col = colblk + cb0 + (n >> 1) * 128 + (n & 1) * 16;
                const float bv = b0[col];
                #pragma unroll
                for (int r = 0; r < 4; ++r)
                    Co[(size_t)(row + r) * EMBED + col] = acc[m][n][r] + bv;
            }
        }
    }
#undef PH_END
#undef PH_MID
#undef MM
#undef LDB
#undef LDA
#undef STAGE_A
#undef STAGE_B
}

// ---------- R9 GEMM (proven): 128x64 tile, 2-barrier loop; out-proj only.
// 1024 blocks, ~5 waves/SIMD -> latency hidden by TLP. R12: +XCD swizzle. ----
__global__ __launch_bounds__(256, 5) void gemm_bf16_128(const short* __restrict__ A,
                                                        const short* __restrict__ BT0,
                                                        const short* __restrict__ BT1,
                                                        const short* __restrict__ BT2,
                                                        const float* __restrict__ b0,
                                                        const float* __restrict__ b1,
                                                        const float* __restrict__ b2,
                                                        void* __restrict__ C0,
                                                        void* __restrict__ C1,
                                                        void* __restrict__ C2,
                                                        int mode) {
    const int z = blockIdx.z;
    const short* BT = (z == 0) ? BT0 : (z == 1) ? BT1 : BT2;
    const float* bias = (z == 0) ? b0 : (z == 1) ? b1 : b2;
    const float bsc = (mode == 0 && z == 0) ? SL2E : 1.0f;
    __shared__ short As[128 * 64];   // [row][k], 16B chunks XOR-swizzled
    __shared__ short Bs[64 * 64];    // [col(n)][k]
    const int tid = threadIdx.x;
    const int wave = tid >> 6, lane = tid & 63;
    const int c = lane & 15, quad = lane >> 4;
    const int sw = c & 7;
    // T1 swizzle: grid (16, 64) = 1024 blocks, 128/XCD -> 8 row-panels/XCD
    const int hid = blockIdx.y * 16 + blockIdx.x;
    const int tle = (hid & 7) * 128 + (hid >> 3);
    const int bx = tle & 15, by = tle >> 4;
    const int row0 = by * 128, col0 = bx * 64;
    f32x4 acc[2][4] = {};
    for (int k0 = 0; k0 < EMBED; k0 += 64) {
        #pragma unroll
        for (int it = 0; it < 4; ++it) {   // A: 1024 chunks
            int ci = (it * 4 + wave) * 64 + lane;
            int row = ci >> 3, g = (ci & 7) ^ (row & 7);   // swizzled source chunk
            async16(&A[(size_t)(row0 + row) * EMBED + k0 + g * 8], &As[(it * 4 + wave) * 512]);
        }
        #pragma unroll
        for (int it = 0; it < 2; ++it) {   // B: 512 chunks
            int ci = (it * 4 + wave) * 64 + lane;
            int row = ci >> 3, g = (ci & 7) ^ (row & 7);
            async16(&BT[(size_t)(col0 + row) * EMBED + k0 + g * 8], &Bs[(it * 4 + wave) * 512]);
        }
        __syncthreads();
        #pragma unroll
        for (int ks = 0; ks < 2; ++ks) {
            bf16x8 af[2], bfr[4];
            #pragma unroll
            for (int i = 0; i < 2; ++i)
                af[i] = *(const bf16x8*)&As[(wave * 32 + i * 16 + c) * 64 + ((ks * 4 + quad) ^ sw) * 8];
            #pragma unroll
            for (int j = 0; j < 4; ++j)
                bfr[j] = *(const bf16x8*)&Bs[(j * 16 + c) * 64 + ((ks * 4 + quad) ^ sw) * 8];
            #pragma unroll
            for (int i = 0; i < 2; ++i)
                #pragma unroll
                for (int j = 0; j < 4; ++j)
                    acc[i][j] = __builtin_amdgcn_mfma_f32_16x16x32_bf16(af[i], bfr[j], acc[i][j], 0, 0, 0);
        }
        __syncthreads();
    }
    if (mode == 0 && z == 2) {
        short* Vt = (short*)C2;
        const int b = row0 >> 11, s0 = (row0 & 2047) + wave * 32;
        const int bh = b * NHEADS + bx;
        #pragma unroll
        for (int i = 0; i < 2; ++i)
            #pragma unroll
            for (int j = 0; j < 4; ++j) {
                int d = j * 16 + c;
                float bv = bias[col0 + d];
                int s = s0 + i * 16 + quad * 4;
                u32x2 o = { pkbf(acc[i][j][0] + bv, acc[i][j][1] + bv),
                            pkbf(acc[i][j][2] + bv, acc[i][j][3] + bv) };
                *(u32x2*)&Vt[((size_t)bh * HDIM + d) * SEQ + s] = o;
            }
    } else {
        void* Cout = (z == 0) ? C0 : (z == 1) ? C1 : C2;
        #pragma unroll
        for (int i = 0; i < 2; ++i)
            #pragma unroll
            for (int j = 0; j < 4; ++j) {
                int colb = col0 + j * 16 + c;
                float bv = bias[colb] * bsc;
                #pragma unroll
                for (int r = 0; r < 4; ++r) {
                    int row = row0 + wave * 32 + i * 16 + quad * 4 + r;
                    float v = acc[i][j][r] + bv;
                    if (mode == 0) ((short*)Cout)[(size_t)row * EMBED + colb] = f2bf(v);
                    else           ((float*)Cout)[(size_t)row * EMBED + colb] = v;
                }
            }
    }
}

// ---------- MFMA flash attention v3 (R12): double-buffered K/V pipeline ----
// Per tile: issue stage(t+1) DMAs into buf^1 (overlaps whole compute), compute
// tile t, ONE explicit vmcnt(0) (cheap - DMAs landed during compute) + ONE raw
// s_barrier (was 2x __syncthreads with full vmcnt drains -> staging latency
// exposed every tile).  Race-freedom: stage(t+1) writes the buffer whose last
// reader finished before the barrier this stage follows; compute reads cannot
// hoist above the previous iteration's memory-clobber asm.  +T5 setprio
// around both MFMA clusters; +T1 XCD swizzle (8 bh/XCD = 4MB K/V = L2-sized).
__global__ __launch_bounds__(256, 3) void attn_mfma(const short* __restrict__ Qb,
                                                    const short* __restrict__ Kb,
                                                    const short* __restrict__ Vt,
                                                    short* __restrict__ Ob) {
    __shared__ short SH[16384];      // K[2][4096] | V[2][4096]; 32KB; O-tr reuse
    const int tid = threadIdx.x;
    const int wave = tid >> 6, lane = tid & 63;
    const int l31 = lane & 31, h = lane >> 5;
    const int swz = l31 & 7;
    // T1 swizzle: grid (16 qb, 64 bh) = 1024 blocks
    const int hid = blockIdx.y * 16 + blockIdx.x;
    const int tle = (hid & 7) * 128 + (hid >> 3);
    const int qb = tle & 15, bh = tle >> 4;
    const int b = bh >> 4, hd = bh & 15;
    const size_t base = (size_t)b * SEQ * EMBED + (size_t)hd * HDIM;
    const size_t vbase = (size_t)bh * HDIM * SEQ;
    const int q0 = qb * 128;

    // Q B-frags for the whole kernel: n=q=l31, k(d) = ks*16 + h*8 + j
    bf16x8 qf[4];
    #pragma unroll
    for (int ks = 0; ks < 4; ++ks)
        qf[ks] = *(const bf16x8*)&Qb[base + (size_t)(q0 + wave * 32 + l31) * EMBED + ks * 16 + h * 8];

    // hoisted staging pointers (advance by constant per k-tile)
    const short* kp[2];
    const short* vp[2];
    int ldofs[2];
    #pragma unroll
    for (int it = 0; it < 2; ++it) {
        int ci = (it * 4 + wave) * 64 + lane;
        int row = ci >> 3, g = (ci & 7) ^ (row & 7);
        kp[it] = Kb + base + (size_t)row * EMBED + g * 8;
        vp[it] = Vt + vbase + (size_t)row * SEQ + g * 8;
        ldofs[it] = (it * 4 + wave) * 512;          // wave-uniform LDS base
    }

    f32x16 O[2] = {};
    f32x2 ls = {0.0f, 0.0f};

    // prologue: stage tile 0 into buf0
    #pragma unroll
    for (int it = 0; it < 2; ++it) {
        async16(kp[it], &SH[ldofs[it]]);
        async16(vp[it], &SH[8192 + ldofs[it]]);
        kp[it] += 64 * EMBED;
        vp[it] += 64;
    }
    asm volatile("s_waitcnt vmcnt(0)" ::: "memory");
    __builtin_amdgcn_s_barrier();

    #pragma unroll 2
    for (int kt = 0; kt < SEQ / 64; ++kt) {
        const int bo = (kt & 1) * 4096;             // current buffer offset
        const short* Ks = SH + bo;
        const short* Vs = SH + 8192 + bo;
        if (kt < SEQ / 64 - 1) {                    // issue next-tile DMAs early
            const int nbo = 4096 - bo;
            #pragma unroll
            for (int it = 0; it < 2; ++it) {
                async16(kp[it], &SH[nbo + ldofs[it]]);
                async16(vp[it], &SH[8192 + nbo + ldofs[it]]);
                kp[it] += 64 * EMBED;
                vp[it] += 64;
            }
        }

        // S^T[key][q] for 64 keys x wave's 32 q
        f32x16 st[2] = {};
        __builtin_amdgcn_s_setprio(1);
        #pragma unroll
        for (int nt = 0; nt < 2; ++nt)
            #pragma unroll
            for (int ks = 0; ks < 4; ++ks) {
                bf16x8 ak = *(const bf16x8*)&Ks[(nt * 32 + l31) * 64 + ((ks * 2 + h) ^ swz) * 8];
                st[nt] = __builtin_amdgcn_mfma_f32_32x32x16_bf16(ak, qf[ks], st[nt], 0, 0, 0);
            }
        __builtin_amdgcn_s_setprio(0);

        // P = exp2(S) (scale pre-folded); pack pairs to bf16; accumulate l
        u32 pk[2][8];
        #pragma unroll
        for (int nt = 0; nt < 2; ++nt)
            #pragma unroll
            for (int i = 0; i < 8; ++i) {
                float e0 = fexp2(st[nt][2 * i]), e1 = fexp2(st[nt][2 * i + 1]);
                f32x2 e = { e0, e1 };
                ls += e;
                pk[nt][i] = pkbf(e0, e1);
            }

        // O^T += V^T . P^T ; P^T B-frag per 16-key step via half-exchange
        __builtin_amdgcn_s_setprio(1);
        #pragma unroll
        for (int ks = 0; ks < 4; ++ks) {
            const int nt = ks >> 1, bs = (ks & 1) * 4;
            u32x4 fr;
#if __has_builtin(__builtin_amdgcn_permlane32_swap)
            i32x2 sA = __builtin_amdgcn_permlane32_swap((int)pk[nt][bs + 0], (int)pk[nt][bs + 2], false, false);
            i32x2 sB = __builtin_amdgcn_permlane32_swap((int)pk[nt][bs + 1], (int)pk[nt][bs + 3], false, false);
            fr.x = (u32)sA.x; fr.y = (u32)sB.x; fr.z = (u32)sA.y; fr.w = (u32)sB.y;
#else
            u32 s0 = h ? pk[nt][bs + 0] : pk[nt][bs + 2];
            u32 s1 = h ? pk[nt][bs + 1] : pk[nt][bs + 3];
            u32 r0 = (u32)__shfl_xor((int)s0, 32);
            u32 r1 = (u32)__shfl_xor((int)s1, 32);
            fr.x = h ? r0 : pk[nt][bs + 0];
            fr.y = h ? r1 : pk[nt][bs + 1];
            fr.z = h ? pk[nt][bs + 2] : r0;
            fr.w = h ? pk[nt][bs + 3] : r1;
#endif
            bf16x8 pf = __builtin_bit_cast(bf16x8, fr);
            #pragma unroll
            for (int mt = 0; mt < 2; ++mt) {
                bf16x8 vf = *(const bf16x8*)&Vs[(mt * 32 + l31) * 64 + ((ks * 2 + h) ^ swz) * 8];
                O[mt] = __builtin_amdgcn_mfma_f32_32x32x16_bf16(vf, pf, O[mt], 0, 0, 0);
            }
        }
        __builtin_amdgcn_s_setprio(0);

        // next tile's DMAs landed during compute; make them visible to all
        asm volatile("s_waitcnt vmcnt(0)" ::: "memory");
        __builtin_amdgcn_s_barrier();
    }

    // finalize: partner lane holds the other half of this q's key-sum
    float lsum = ls.x + ls.y;
    lsum += __shfl_xor(lsum, 32);
    float inv = 1.0f / lsum;

    // O^T[d][q]: col=q=l31, d = mt*32 + (reg&3) + 8*(reg>>2) + 4h.
    // Write bf16 to LDS (XOR-swizzled 8B units), then read rows -> coalesced.
    const int wbase = wave * 2048;
    #pragma unroll
    for (int mt = 0; mt < 2; ++mt)
        #pragma unroll
        for (int m = 0; m < 4; ++m) {
            u32x2 wv;
            wv.x = pkbf(O[mt][4 * m + 0] * inv, O[mt][4 * m + 1] * inv);
            wv.y = pkbf(O[mt][4 * m + 2] * inv, O[mt][4 * m + 3] * inv);
            int u = mt * 8 + 2 * m + h;               // 8B unit index (d = u*4)
            int su = u ^ ((l31 & 7) << 1);
            *(u32x2*)&SH[wbase + l31 * 64 + su * 4] = wv;
        }
    __syncthreads();
    // full tile = 1024 x 16B chunks (4 waves x 32 q x 8 d-chunks)
    #pragma unroll
    for (int p = 0; p < 4; ++p) {
        int ci = p * 256 + tid;
        int wq = ci >> 8, rem = ci & 255;
        int r = rem >> 3, cch = rem & 7;
        int su = (2 * cch) ^ ((r & 7) << 1);
        bf16x8 val = *(const bf16x8*)&SH[wq * 2048 + r * 64 + su * 4];
        *(bf16x8*)&Ob[base + (size_t)(q0 + wq * 32 + r) * EMBED + cch * 8] = val;
    }
}

extern "C" void kernel_launch(void* const* d_in, const int* in_sizes, int n_in,
                              void* d_out, int out_size, void* d_ws, size_t ws_size,
                              hipStream_t stream)
{
    const float* X  = (const float*)d_in[0];
    const float* Wq = (const float*)d_in[1];
    const float* bq = (const float*)d_in[2];
    const float* Wk = (const float*)d_in[3];
    const float* bk = (const float*)d_in[4];
    const float* Wv = (const float*)d_in[5];
    const float* bv = (const float*)d_in[6];
    const float* Wo = (const float*)d_in[7];
    const float* bo = (const float*)d_in[8];
    float* out = (float*)d_out;

    const size_t NE = (size_t)ROWS * EMBED;       // 8M elements
    short* Xbf = (short*)d_ws;                    // 16 MB
    short* Qb  = Xbf + NE;                        // 16 MB (also attention O)
    short* Kb  = Qb + NE;                         // 16 MB
    short* Vtb = Kb + NE;                         // 16 MB  [bh][d][s]
    short* WqT = Vtb + NE;                        // 2 MB each; WqT/WkT/WvT are
    short* WkT = WqT + (size_t)EMBED * EMBED;     //   CONTIGUOUS = combined
    short* WvT = WkT + (size_t)EMBED * EMBED;     //   Wqkv^T [3072][1024]
    short* WoT = WvT + (size_t)EMBED * EMBED;     // total 72 MB

    convert_f32_bf16<<<(ROWS * EMBED) / 1024, 256, 0, stream>>>(X, Xbf);
    dim3 gw(16, 16, 4);
    transpose_w4<<<gw, 256, 0, stream>>>(Wq, Wk, Wv, Wo, WqT, WkT, WvT, WoT);

    // combined QKV via 256^2 8-phase kernel: grid (3072/256, 8192/256) = 384
    dim3 gq(12, 32, 1);
    gemm256<<<gq, 512, 0, stream>>>(Xbf, WqT, bq, bk, bv, Qb, Kb, Vtb, 0);

    dim3 gt(SEQ / 128, BATCH * NHEADS);           // (16, 64)
    attn_mfma<<<gt, 256, 0, stream>>>(Qb, Kb, Vtb, Qb);   // O aliases Qb

    // out-proj via proven 128x64 kernel: 1024 blocks, TLP-hidden
    dim3 gg(EMBED / 64, ROWS / 128, 1);
    gemm_bf16_128<<<gg, 256, 0, stream>>>(Qb, WoT, WoT, WoT, bo, bo, bo,
                                          out, out, out, 1);
}

// Round 4
// 277.079 us; speedup vs baseline: 1.0060x; 1.0060x over previous
//
#include <hip/hip_runtime.h>
#include <hip/hip_bf16.h>

#define EMBED 1024
#define NHEADS 16
#define HDIM 64
#define SEQ 2048
#define BATCH 4
#define ROWS (BATCH * SEQ) /* 8192 */

typedef __attribute__((ext_vector_type(8))) short bf16x8;   // 8 bf16 = 4 VGPRs
typedef __attribute__((ext_vector_type(4))) float f32x4;
typedef __attribute__((ext_vector_type(2))) float f32x2;
typedef __attribute__((ext_vector_type(16))) float f32x16;
typedef __attribute__((ext_vector_type(4))) unsigned int u32x4;
typedef __attribute__((ext_vector_type(2))) unsigned int u32x2;
typedef __attribute__((ext_vector_type(2))) int i32x2;
typedef unsigned int u32;

#define SL2E 0.18033688011112042f  /* 0.125 * log2(e) */

__device__ __forceinline__ short f2bf(float f) {            // RTNA fp32->bf16 (2 ops)
    u32 u = __builtin_bit_cast(u32, f) + 0x8000u;
    return (short)(u >> 16);
}

__device__ __forceinline__ u32 pkbf(float a, float b) {     // {bf16(a)|bf16(b)<<16}, 3 ops
    u32 ua = __builtin_bit_cast(u32, a) + 0x8000u;
    u32 ub = __builtin_bit_cast(u32, b) + 0x8000u;
    return __builtin_amdgcn_perm(ua, ub, 0x03020706u);      // v_perm_b32: {a.hi16, b.hi16}
}

__device__ __forceinline__ float fexp2(float x) {
#if __has_builtin(__builtin_amdgcn_exp2f)
    return __builtin_amdgcn_exp2f(x);                       // bare v_exp_f32
#else
    return exp2f(x);
#endif
}

__device__ __forceinline__ void async16(const void* g, void* l) {
    __builtin_amdgcn_global_load_lds((const __attribute__((address_space(1))) u32*)g,
                                     (__attribute__((address_space(3))) u32*)l, 16, 0, 0);
}

// ---------- fp32 -> bf16 elementwise (X) ----------
__global__ __launch_bounds__(256) void convert_f32_bf16(const float* __restrict__ in,
                                                        short* __restrict__ out) {
    int i = (blockIdx.x * 256 + threadIdx.x) * 4;
    float4 v = *(const float4*)&in[i];
    u32x2 o = { pkbf(v.x, v.y), pkbf(v.z, v.w) };
    *(u32x2*)&out[i] = o;
}

// ---------- W[K][N] fp32 -> WT[N][K] bf16; z==0 (Wq) pre-scaled by SL2E ----------
__global__ __launch_bounds__(256) void transpose_w4(const float* __restrict__ W0,
                                                    const float* __restrict__ W1,
                                                    const float* __restrict__ W2,
                                                    const float* __restrict__ W3,
                                                    short* __restrict__ T0,
                                                    short* __restrict__ T1,
                                                    short* __restrict__ T2,
                                                    short* __restrict__ T3) {
    const int z = blockIdx.z;
    const float* W = (z == 0) ? W0 : (z == 1) ? W1 : (z == 2) ? W2 : W3;
    short* WT = (z == 0) ? T0 : (z == 1) ? T1 : (z == 2) ? T2 : T3;
    const float sc = (z == 0) ? SL2E : 1.0f;
    __shared__ float T[64][65];
    const int k0 = blockIdx.y * 64, n0 = blockIdx.x * 64;
    const int rr = threadIdx.x >> 4, cc = (threadIdx.x & 15) * 4;
    #pragma unroll
    for (int p = 0; p < 4; ++p) {
        int r = p * 16 + rr;
        float4 v = *(const float4*)&W[(size_t)(k0 + r) * EMBED + n0 + cc];
        T[r][cc] = v.x * sc; T[r][cc + 1] = v.y * sc; T[r][cc + 2] = v.z * sc; T[r][cc + 3] = v.w * sc;
    }
    __syncthreads();
    #pragma unroll
    for (int p = 0; p < 4; ++p) {
        int r = p * 16 + rr;  // n offset
        u32x2 o = { pkbf(T[cc][r], T[cc + 1][r]), pkbf(T[cc + 2][r], T[cc + 3][r]) };
        *(u32x2*)&WT[(size_t)(n0 + r) * EMBED + k0 + cc] = o;
    }
}

// ============================================================================
// R13: 128x256 8-phase GEMM (R11's verified register-reuse schedule at a
// grid-friendly tile).  Rationale: 256^2 QKV = 384 blocks at 1 blk/CU = 1.5
// scheduling rounds (25% idle CU-time); out-proj 256^2 = 128 blocks (half the
// chip idle).  128x256 gives QKV 768 = 3 exact rounds, out-proj 256 = 1 round.
// 512 thr = 8 waves (2M x 4N), per-wave 64x64, BK=64, LDS 96 KiB, 1 blk/CU.
// Quadrant order per K-tile: (0,0) (0,1) (1,1) (1,0); frags persist in regs:
//   aU = current A-half (MH0 @ph1, MH1 @ph3), bE = B-NH0 (ph1, reused ph4),
//   bO = B-NH1 (ph2, reused ph3).  Phase ds_read b128 counts: 8/4/4/0.
// Stage units (16KB = 2 async16/thread): per K-tile {B0, B1, A}; tile t
// stages tile t+2 into buf[t&1]:  ph2: B0 (B0's last LDS-read is ph1; the
// ph2 stage is issued after ph1's ENDING barrier, and every wave's ph1 reads
// completed at its own ph1 lgkmcnt(0) before that barrier)  ph3: B1 (last
// read ph2)  ph4: A (last read ph3).  vmcnt(6) once per K-tile at ph4 =
// exactly the 6 loads for t+2 outstanding -> t+1 fully landed.  Never 0 in
// the loop.  Tail stages wrap (&15) into dead regions; final vmcnt(0) drains
// before LDS dealloc.
// mode 0: combined QKV (BT = [3072][1024]): cols/1024 selects Q bf16 (bias
// pre-scaled SL2E) / K bf16 / Vt[bh][d][s].   mode 1: fp32 row-major out.
// ============================================================================
__global__ __launch_bounds__(512, 2) void gemm_p128(const short* __restrict__ A,
                                                    const short* __restrict__ BT,
                                                    const float* __restrict__ b0,
                                                    const float* __restrict__ b1,
                                                    const float* __restrict__ b2,
                                                    void* __restrict__ C0,
                                                    void* __restrict__ C1,
                                                    void* __restrict__ C2,
                                                    int mode) {
    __shared__ short As[2][8192];    // [buf][128 rows][64 k], 16B chunks XOR-swizzled
    __shared__ short Bs[2][16384];   // [buf][256 cols][64 k]
    const int tid = threadIdx.x;
    const int lane = tid & 63;
    const int wid = tid >> 6;
    const int c16 = lane & 15, quad = lane >> 4, sw = c16 & 7;
    const int wm = wid >> 2, wn = wid & 3;            // 2M x 4N wave grid
    // T1: bijective chunked XCD swizzle (nwg % 8 == 0 for both launches)
    const int gx = gridDim.x;
    const int hid = blockIdx.y * gx + blockIdx.x;
    const int cpx = (gx * gridDim.y) >> 3;
    const int tle = (hid & 7) * cpx + (hid >> 3);
    const int bx = tle % gx, by = tle / gx;
    const int rowblk = by * 128, colblk = bx * 256;

    // staging: thread t owns 16B chunks c = t (+512, +1024, +1536); chunk c:
    // row = c>>3, global k-chunk g = (c&7)^(row&7)  (read-side XOR swizzle
    // inverse pre-applied to the GLOBAL source; LDS dest stays linear).
    // +512 chunks = +64 rows; row&7 unchanged -> same g.
    const int r0 = tid >> 3;                          // 0..63
    const int g0 = (tid & 7) ^ (r0 & 7);
    const short* aS0 = A + (size_t)(rowblk + r0) * EMBED + g0 * 8;
    const short* bS0 = BT + (size_t)(colblk + r0) * EMBED + g0 * 8;

#define STAGE_A(SBUF, V) do { \
    const short* _s = aS0 + (V) * 64; \
    async16(_s,         &As[SBUF][tid * 8]); \
    async16(_s + 65536, &As[SBUF][tid * 8 + 4096]); \
} while (0)
#define STAGE_B0(SBUF, V) do { \
    const short* _s = bS0 + (V) * 64; \
    async16(_s,         &Bs[SBUF][tid * 8]); \
    async16(_s + 65536, &Bs[SBUF][tid * 8 + 4096]); \
} while (0)
#define STAGE_B1(SBUF, V) do { \
    const short* _s = bS0 + 131072 + (V) * 64; \
    async16(_s,         &Bs[SBUF][tid * 8 + 8192]); \
    async16(_s + 65536, &Bs[SBUF][tid * 8 + 12288]); \
} while (0)

    f32x4 acc[4][4] = {};            // [m = MH*2+fm][n = NH*2+fn], static idx
    bf16x8 aU[2][2], bE[2][2], bO[2][2];

#define LDA(BUF, MH) do { \
    _Pragma("unroll") \
    for (int fm = 0; fm < 2; ++fm) { \
        const int row = wm * 64 + (MH) * 32 + fm * 16 + c16; \
        _Pragma("unroll") \
        for (int ks = 0; ks < 2; ++ks) \
            aU[fm][ks] = *(const bf16x8*)&As[BUF][row * 64 + ((ks * 4 + quad) ^ sw) * 8]; \
    } \
} while (0)
#define LDB(BUF, NH, DST) do { \
    _Pragma("unroll") \
    for (int fn = 0; fn < 2; ++fn) { \
        const int col = wn * 64 + (NH) * 32 + fn * 16 + c16; \
        _Pragma("unroll") \
        for (int ks = 0; ks < 2; ++ks) \
            DST[fn][ks] = *(const bf16x8*)&Bs[BUF][col * 64 + ((ks * 4 + quad) ^ sw) * 8]; \
    } \
} while (0)
#define MM(MB, NB, BM_) do { \
    _Pragma("unroll") \
    for (int fm = 0; fm < 2; ++fm) \
        _Pragma("unroll") \
        for (int fn = 0; fn < 2; ++fn) \
            _Pragma("unroll") \
            for (int ks = 0; ks < 2; ++ks) \
                acc[(MB) + fm][(NB) + fn] = \
                    __builtin_amdgcn_mfma_f32_16x16x32_bf16(aU[fm][ks], BM_[fn][ks], \
                        acc[(MB) + fm][(NB) + fn], 0, 0, 0); \
} while (0)
#define PH_MID() do { \
    __builtin_amdgcn_s_barrier(); \
    asm volatile("s_waitcnt lgkmcnt(0)" ::: "memory"); \
    __builtin_amdgcn_s_setprio(1); \
} while (0)
#define PH_END(VM) do { \
    __builtin_amdgcn_s_setprio(0); \
    if (VM) asm volatile("s_waitcnt vmcnt(6)" ::: "memory"); \
    __builtin_amdgcn_s_barrier(); \
} while (0)

    // prologue: tile0 (buf0) + tile1 (buf1) staged; wait tile0 (6 outstanding)
    STAGE_B0(0, 0); STAGE_A(0, 0); STAGE_B1(0, 0);
    STAGE_B0(1, 1); STAGE_A(1, 1); STAGE_B1(1, 1);
    asm volatile("s_waitcnt vmcnt(6)" ::: "memory");
    __builtin_amdgcn_s_barrier();

    #pragma unroll 1
    for (int it = 0; it < 8; ++it) {
        const int u = 2 * it;
        const int v2 = (u + 2) & 15, v3 = (u + 3) & 15;
        // ---- tile u (buf0); stage tile u+2 -> buf0 ----
        LDA(0, 0); LDB(0, 0, bE);                     PH_MID(); MM(0, 0, bE); PH_END(0);
        LDB(0, 1, bO);            STAGE_B0(0, v2);    PH_MID(); MM(0, 2, bO); PH_END(0);
        LDA(0, 1);                STAGE_B1(0, v2);    PH_MID(); MM(2, 2, bO); PH_END(0);
        /* no ds_reads */         STAGE_A(0, v2);     PH_MID(); MM(2, 0, bE); PH_END(1);
        // ---- tile u+1 (buf1); stage tile u+3 -> buf1 ----
        LDA(1, 0); LDB(1, 0, bE);                     PH_MID(); MM(0, 0, bE); PH_END(0);
        LDB(1, 1, bO);            STAGE_B0(1, v3);    PH_MID(); MM(0, 2, bO); PH_END(0);
        LDA(1, 1);                STAGE_B1(1, v3);    PH_MID(); MM(2, 2, bO); PH_END(0);
        /* no ds_reads */         STAGE_A(1, v3);     PH_MID(); MM(2, 0, bE); PH_END(1);
    }

    // drain dangling prefetches before the wave retires
    asm volatile("s_waitcnt vmcnt(0)" ::: "memory");

    // epilogue: C/D frag layout col = lane&15, row = quad*4 + reg.
    // acc[m][n]: row-off = (m>>1)*32 + (m&1)*16, col-off = (n>>1)*32 + (n&1)*16
    const int rb0 = rowblk + wm * 64 + quad * 4;
    const int cb0 = wn * 64 + c16;
    if (mode == 0) {
        const int z = colblk >> 10;               // block's 256 cols lie in one of Q/K/V
        const int cm = colblk & 1023;
        const float* bias = (z == 0) ? b0 : (z == 1) ? b1 : b2;
        if (z == 2) {
            short* Vt = (short*)C2;               // Vt[bh][d][s], 4 consecutive s per frag
            #pragma unroll
            for (int m = 0; m < 4; ++m) {
                const int row = rb0 + (m >> 1) * 32 + (m & 1) * 16;
                const int b = row >> 11, s = row & 2047;
                #pragma unroll
                for (int n = 0; n < 4; ++n) {
                    const int cv = cm + cb0 + (n >> 1) * 32 + (n & 1) * 16;
                    const int head = cv >> 6, d = cv & 63;
                    const float bv = bias[cv];
                    u32x2 o = { pkbf(acc[m][n][0] + bv, acc[m][n][1] + bv),
                                pkbf(acc[m][n][2] + bv, acc[m][n][3] + bv) };
                    *(u32x2*)&Vt[((size_t)(b * NHEADS + head) * HDIM + d) * SEQ + s] = o;
                }
            }
        } else {
            short* Cq = (short*)((z == 0) ? C0 : C1);
            const float bsc = (z == 0) ? SL2E : 1.0f;
            #pragma unroll
            for (int m = 0; m < 4; ++m) {
                const int row = rb0 + (m >> 1) * 32 + (m & 1) * 16;
                #pragma unroll
                for (int n = 0; n < 4; ++n) {
                    const int col = cm + cb0 + (n >> 1) * 32 + (n & 1) * 16;
                    const float bv = bias[col] * bsc;
                    #pragma unroll
                    for (int r = 0; r < 4; ++r)
                        Cq[(size_t)(row + r) * EMBED + col] = f2bf(acc[m][n][r] + bv);
                }
            }
        }
    } else {
        float* Co = (float*)C0;
        #pragma unroll
        for (int m = 0; m < 4; ++m) {
            const int row = rb0 + (m >> 1) * 32 + (m & 1) * 16;
            #pragma unroll
            for (int n = 0; n < 4; ++n) {
                const int col = colblk + cb0 + (n >> 1) * 32 + (n & 1) * 16;
                const float bv = b0[col];
                #pragma unroll
                for (int r = 0; r < 4; ++r)
                    Co[(size_t)(row + r) * EMBED + col] = acc[m][n][r] + bv;
            }
        }
    }
#undef PH_END
#undef PH_MID
#undef MM
#undef LDB
#undef LDA
#undef STAGE_B1
#undef STAGE_B0
#undef STAGE_A
}

// ---------- MFMA flash attention v3 (unchanged from R12 — control) ----------
// Double-buffered K/V; one vmcnt(0)+s_barrier per tile; T5 setprio; T1 XCD
// swizzle (8 bh/XCD -> K/V L2-resident; FETCH 139MB -> 24.6MB measured).
__global__ __launch_bounds__(256, 3) void attn_mfma(const short* __restrict__ Qb,
                                                    const short* __restrict__ Kb,
                                                    const short* __restrict__ Vt,
                                                    short* __restrict__ Ob) {
    __shared__ short SH[16384];      // K[2][4096] | V[2][4096]; 32KB; O-tr reuse
    const int tid = threadIdx.x;
    const int wave = tid >> 6, lane = tid & 63;
    const int l31 = lane & 31, h = lane >> 5;
    const int swz = l31 & 7;
    // T1 swizzle: grid (16 qb, 64 bh) = 1024 blocks
    const int hid = blockIdx.y * 16 + blockIdx.x;
    const int tle = (hid & 7) * 128 + (hid >> 3);
    const int qb = tle & 15, bh = tle >> 4;
    const int b = bh >> 4, hd = bh & 15;
    const size_t base = (size_t)b * SEQ * EMBED + (size_t)hd * HDIM;
    const size_t vbase = (size_t)bh * HDIM * SEQ;
    const int q0 = qb * 128;

    // Q B-frags for the whole kernel: n=q=l31, k(d) = ks*16 + h*8 + j
    bf16x8 qf[4];
    #pragma unroll
    for (int ks = 0; ks < 4; ++ks)
        qf[ks] = *(const bf16x8*)&Qb[base + (size_t)(q0 + wave * 32 + l31) * EMBED + ks * 16 + h * 8];

    // hoisted staging pointers (advance by constant per k-tile)
    const short* kp[2];
    const short* vp[2];
    int ldofs[2];
    #pragma unroll
    for (int it = 0; it < 2; ++it) {
        int ci = (it * 4 + wave) * 64 + lane;
        int row = ci >> 3, g = (ci & 7) ^ (row & 7);
        kp[it] = Kb + base + (size_t)row * EMBED + g * 8;
        vp[it] = Vt + vbase + (size_t)row * SEQ + g * 8;
        ldofs[it] = (it * 4 + wave) * 512;          // wave-uniform LDS base
    }

    f32x16 O[2] = {};
    f32x2 ls = {0.0f, 0.0f};

    // prologue: stage tile 0 into buf0
    #pragma unroll
    for (int it = 0; it < 2; ++it) {
        async16(kp[it], &SH[ldofs[it]]);
        async16(vp[it], &SH[8192 + ldofs[it]]);
        kp[it] += 64 * EMBED;
        vp[it] += 64;
    }
    asm volatile("s_waitcnt vmcnt(0)" ::: "memory");
    __builtin_amdgcn_s_barrier();

    #pragma unroll 2
    for (int kt = 0; kt < SEQ / 64; ++kt) {
        const int bo = (kt & 1) * 4096;             // current buffer offset
        const short* Ks = SH + bo;
        const short* Vs = SH + 8192 + bo;
        if (kt < SEQ / 64 - 1) {                    // issue next-tile DMAs early
            const int nbo = 4096 - bo;
            #pragma unroll
            for (int it = 0; it < 2; ++it) {
                async16(kp[it], &SH[nbo + ldofs[it]]);
                async16(vp[it], &SH[8192 + nbo + ldofs[it]]);
                kp[it] += 64 * EMBED;
                vp[it] += 64;
            }
        }

        // S^T[key][q] for 64 keys x wave's 32 q
        f32x16 st[2] = {};
        __builtin_amdgcn_s_setprio(1);
        #pragma unroll
        for (int nt = 0; nt < 2; ++nt)
            #pragma unroll
            for (int ks = 0; ks < 4; ++ks) {
                bf16x8 ak = *(const bf16x8*)&Ks[(nt * 32 + l31) * 64 + ((ks * 2 + h) ^ swz) * 8];
                st[nt] = __builtin_amdgcn_mfma_f32_32x32x16_bf16(ak, qf[ks], st[nt], 0, 0, 0);
            }
        __builtin_amdgcn_s_setprio(0);

        // P = exp2(S) (scale pre-folded); pack pairs to bf16; accumulate l
        u32 pk[2][8];
        #pragma unroll
        for (int nt = 0; nt < 2; ++nt)
            #pragma unroll
            for (int i = 0; i < 8; ++i) {
                float e0 = fexp2(st[nt][2 * i]), e1 = fexp2(st[nt][2 * i + 1]);
                f32x2 e = { e0, e1 };
                ls += e;
                pk[nt][i] = pkbf(e0, e1);
            }

        // O^T += V^T . P^T ; P^T B-frag per 16-key step via half-exchange
        __builtin_amdgcn_s_setprio(1);
        #pragma unroll
        for (int ks = 0; ks < 4; ++ks) {
            const int nt = ks >> 1, bs = (ks & 1) * 4;
            u32x4 fr;
#if __has_builtin(__builtin_amdgcn_permlane32_swap)
            i32x2 sA = __builtin_amdgcn_permlane32_swap((int)pk[nt][bs + 0], (int)pk[nt][bs + 2], false, false);
            i32x2 sB = __builtin_amdgcn_permlane32_swap((int)pk[nt][bs + 1], (int)pk[nt][bs + 3], false, false);
            fr.x = (u32)sA.x; fr.y = (u32)sB.x; fr.z = (u32)sA.y; fr.w = (u32)sB.y;
#else
            u32 s0 = h ? pk[nt][bs + 0] : pk[nt][bs + 2];
            u32 s1 = h ? pk[nt][bs + 1] : pk[nt][bs + 3];
            u32 r0 = (u32)__shfl_xor((int)s0, 32);
            u32 r1 = (u32)__shfl_xor((int)s1, 32);
            fr.x = h ? r0 : pk[nt][bs + 0];
            fr.y = h ? r1 : pk[nt][bs + 1];
            fr.z = h ? pk[nt][bs + 2] : r0;
            fr.w = h ? pk[nt][bs + 3] : r1;
#endif
            bf16x8 pf = __builtin_bit_cast(bf16x8, fr);
            #pragma unroll
            for (int mt = 0; mt < 2; ++mt) {
                bf16x8 vf = *(const bf16x8*)&Vs[(mt * 32 + l31) * 64 + ((ks * 2 + h) ^ swz) * 8];
                O[mt] = __builtin_amdgcn_mfma_f32_32x32x16_bf16(vf, pf, O[mt], 0, 0, 0);
            }
        }
        __builtin_amdgcn_s_setprio(0);

        // next tile's DMAs landed during compute; make them visible to all
        asm volatile("s_waitcnt vmcnt(0)" ::: "memory");
        __builtin_amdgcn_s_barrier();
    }

    // finalize: partner lane holds the other half of this q's key-sum
    float lsum = ls.x + ls.y;
    lsum += __shfl_xor(lsum, 32);
    float inv = 1.0f / lsum;

    // O^T[d][q]: col=q=l31, d = mt*32 + (reg&3) + 8*(reg>>2) + 4h.
    // Write bf16 to LDS (XOR-swizzled 8B units), then read rows -> coalesced.
    const int wbase = wave * 2048;
    #pragma unroll
    for (int mt = 0; mt < 2; ++mt)
        #pragma unroll
        for (int m = 0; m < 4; ++m) {
            u32x2 wv;
            wv.x = pkbf(O[mt][4 * m + 0] * inv, O[mt][4 * m + 1] * inv);
            wv.y = pkbf(O[mt][4 * m + 2] * inv, O[mt][4 * m + 3] * inv);
            int u = mt * 8 + 2 * m + h;               // 8B unit index (d = u*4)
            int su = u ^ ((l31 & 7) << 1);
            *(u32x2*)&SH[wbase + l31 * 64 + su * 4] = wv;
        }
    __syncthreads();
    // full tile = 1024 x 16B chunks (4 waves x 32 q x 8 d-chunks)
    #pragma unroll
    for (int p = 0; p < 4; ++p) {
        int ci = p * 256 + tid;
        int wq = ci >> 8, rem = ci & 255;
        int r = rem >> 3, cch = rem & 7;
        int su = (2 * cch) ^ ((r & 7) << 1);
        bf16x8 val = *(const bf16x8*)&SH[wq * 2048 + r * 64 + su * 4];
        *(bf16x8*)&Ob[base + (size_t)(q0 + wq * 32 + r) * EMBED + cch * 8] = val;
    }
}

extern "C" void kernel_launch(void* const* d_in, const int* in_sizes, int n_in,
                              void* d_out, int out_size, void* d_ws, size_t ws_size,
                              hipStream_t stream)
{
    const float* X  = (const float*)d_in[0];
    const float* Wq = (const float*)d_in[1];
    const float* bq = (const float*)d_in[2];
    const float* Wk = (const float*)d_in[3];
    const float* bk = (const float*)d_in[4];
    const float* Wv = (const float*)d_in[5];
    const float* bv = (const float*)d_in[6];
    const float* Wo = (const float*)d_in[7];
    const float* bo = (const float*)d_in[8];
    float* out = (float*)d_out;

    const size_t NE = (size_t)ROWS * EMBED;       // 8M elements
    short* Xbf = (short*)d_ws;                    // 16 MB
    short* Qb  = Xbf + NE;                        // 16 MB (also attention O)
    short* Kb  = Qb + NE;                         // 16 MB
    short* Vtb = Kb + NE;                         // 16 MB  [bh][d][s]
    short* WqT = Vtb + NE;                        // 2 MB each; WqT/WkT/WvT are
    short* WkT = WqT + (size_t)EMBED * EMBED;     //   CONTIGUOUS = combined
    short* WvT = WkT + (size_t)EMBED * EMBED;     //   Wqkv^T [3072][1024]
    short* WoT = WvT + (size_t)EMBED * EMBED;     // total 72 MB

    convert_f32_bf16<<<(ROWS * EMBED) / 1024, 256, 0, stream>>>(X, Xbf);
    dim3 gw(16, 16, 4);
    transpose_w4<<<gw, 256, 0, stream>>>(Wq, Wk, Wv, Wo, WqT, WkT, WvT, WoT);

    // combined QKV: grid (3072/256, 8192/128) = 768 blocks = 3 exact rounds
    dim3 gq(12, 64, 1);
    gemm_p128<<<gq, 512, 0, stream>>>(Xbf, WqT, bq, bk, bv, Qb, Kb, Vtb, 0);

    dim3 gt(SEQ / 128, BATCH * NHEADS);           // (16, 64)
    attn_mfma<<<gt, 256, 0, stream>>>(Qb, Kb, Vtb, Qb);   // O aliases Qb

    // out-proj: grid (1024/256, 8192/128) = 256 blocks = 1 exact round
    dim3 gg(4, 64, 1);
    gemm_p128<<<gg, 512, 0, stream>>>(Qb, WoT, bo, bo, bo, out, out, out, 1);
}

// Round 5
// 270.042 us; speedup vs baseline: 1.0322x; 1.0261x over previous
//
#include <hip/hip_runtime.h>
#include <hip/hip_bf16.h>

#define EMBED 1024
#define NHEADS 16
#define HDIM 64
#define SEQ 2048
#define BATCH 4
#define ROWS (BATCH * SEQ) /* 8192 */

typedef __attribute__((ext_vector_type(8))) short bf16x8;   // 8 bf16 = 4 VGPRs
typedef __attribute__((ext_vector_type(4))) float f32x4;
typedef __attribute__((ext_vector_type(2))) float f32x2;
typedef __attribute__((ext_vector_type(16))) float f32x16;
typedef __attribute__((ext_vector_type(4))) unsigned int u32x4;
typedef __attribute__((ext_vector_type(2))) unsigned int u32x2;
typedef __attribute__((ext_vector_type(2))) int i32x2;
typedef unsigned int u32;

#define SL2E 0.18033688011112042f  /* 0.125 * log2(e) */

__device__ __forceinline__ short f2bf(float f) {            // RTNA fp32->bf16 (2 ops)
    u32 u = __builtin_bit_cast(u32, f) + 0x8000u;
    return (short)(u >> 16);
}

__device__ __forceinline__ u32 pkbf(float a, float b) {     // {bf16(a)|bf16(b)<<16}, 3 ops
    u32 ua = __builtin_bit_cast(u32, a) + 0x8000u;
    u32 ub = __builtin_bit_cast(u32, b) + 0x8000u;
    return __builtin_amdgcn_perm(ua, ub, 0x03020706u);      // v_perm_b32: {a.hi16, b.hi16}
}

__device__ __forceinline__ float fexp2(float x) {
#if __has_builtin(__builtin_amdgcn_exp2f)
    return __builtin_amdgcn_exp2f(x);                       // bare v_exp_f32
#else
    return exp2f(x);
#endif
}

__device__ __forceinline__ void async16(const void* g, void* l) {
    __builtin_amdgcn_global_load_lds((const __attribute__((address_space(1))) u32*)g,
                                     (__attribute__((address_space(3))) u32*)l, 16, 0, 0);
}

// ---------- fp32 -> bf16 elementwise (X) ----------
__global__ __launch_bounds__(256) void convert_f32_bf16(const float* __restrict__ in,
                                                        short* __restrict__ out) {
    int i = (blockIdx.x * 256 + threadIdx.x) * 4;
    float4 v = *(const float4*)&in[i];
    u32x2 o = { pkbf(v.x, v.y), pkbf(v.z, v.w) };
    *(u32x2*)&out[i] = o;
}

// ---------- W[K][N] fp32 -> WT[N][K] bf16; z==0 (Wq) pre-scaled by SL2E ----------
__global__ __launch_bounds__(256) void transpose_w4(const float* __restrict__ W0,
                                                    const float* __restrict__ W1,
                                                    const float* __restrict__ W2,
                                                    const float* __restrict__ W3,
                                                    short* __restrict__ T0,
                                                    short* __restrict__ T1,
                                                    short* __restrict__ T2,
                                                    short* __restrict__ T3) {
    const int z = blockIdx.z;
    const float* W = (z == 0) ? W0 : (z == 1) ? W1 : (z == 2) ? W2 : W3;
    short* WT = (z == 0) ? T0 : (z == 1) ? T1 : (z == 2) ? T2 : T3;
    const float sc = (z == 0) ? SL2E : 1.0f;
    __shared__ float T[64][65];
    const int k0 = blockIdx.y * 64, n0 = blockIdx.x * 64;
    const int rr = threadIdx.x >> 4, cc = (threadIdx.x & 15) * 4;
    #pragma unroll
    for (int p = 0; p < 4; ++p) {
        int r = p * 16 + rr;
        float4 v = *(const float4*)&W[(size_t)(k0 + r) * EMBED + n0 + cc];
        T[r][cc] = v.x * sc; T[r][cc + 1] = v.y * sc; T[r][cc + 2] = v.z * sc; T[r][cc + 3] = v.w * sc;
    }
    __syncthreads();
    #pragma unroll
    for (int p = 0; p < 4; ++p) {
        int r = p * 16 + rr;  // n offset
        u32x2 o = { pkbf(T[cc][r], T[cc + 1][r]), pkbf(T[cc + 2][r], T[cc + 3][r]) };
        *(u32x2*)&WT[(size_t)(n0 + r) * EMBED + k0 + cc] = o;
    }
}

// ============================================================================
// R13 GEMM (unchanged — control this round): 128x256 8-phase register-reuse
// schedule, BK=64, 8 waves, LDS 96 KiB, T1 XCD swizzle, counted vmcnt(6).
// ============================================================================
__global__ __launch_bounds__(512, 2) void gemm_p128(const short* __restrict__ A,
                                                    const short* __restrict__ BT,
                                                    const float* __restrict__ b0,
                                                    const float* __restrict__ b1,
                                                    const float* __restrict__ b2,
                                                    void* __restrict__ C0,
                                                    void* __restrict__ C1,
                                                    void* __restrict__ C2,
                                                    int mode) {
    __shared__ short As[2][8192];    // [buf][128 rows][64 k], 16B chunks XOR-swizzled
    __shared__ short Bs[2][16384];   // [buf][256 cols][64 k]
    const int tid = threadIdx.x;
    const int lane = tid & 63;
    const int wid = tid >> 6;
    const int c16 = lane & 15, quad = lane >> 4, sw = c16 & 7;
    const int wm = wid >> 2, wn = wid & 3;            // 2M x 4N wave grid
    const int gx = gridDim.x;
    const int hid = blockIdx.y * gx + blockIdx.x;
    const int cpx = (gx * gridDim.y) >> 3;
    const int tle = (hid & 7) * cpx + (hid >> 3);
    const int bx = tle % gx, by = tle / gx;
    const int rowblk = by * 128, colblk = bx * 256;

    const int r0 = tid >> 3;                          // 0..63
    const int g0 = (tid & 7) ^ (r0 & 7);
    const short* aS0 = A + (size_t)(rowblk + r0) * EMBED + g0 * 8;
    const short* bS0 = BT + (size_t)(colblk + r0) * EMBED + g0 * 8;

#define STAGE_A(SBUF, V) do { \
    const short* _s = aS0 + (V) * 64; \
    async16(_s,         &As[SBUF][tid * 8]); \
    async16(_s + 65536, &As[SBUF][tid * 8 + 4096]); \
} while (0)
#define STAGE_B0(SBUF, V) do { \
    const short* _s = bS0 + (V) * 64; \
    async16(_s,         &Bs[SBUF][tid * 8]); \
    async16(_s + 65536, &Bs[SBUF][tid * 8 + 4096]); \
} while (0)
#define STAGE_B1(SBUF, V) do { \
    const short* _s = bS0 + 131072 + (V) * 64; \
    async16(_s,         &Bs[SBUF][tid * 8 + 8192]); \
    async16(_s + 65536, &Bs[SBUF][tid * 8 + 12288]); \
} while (0)

    f32x4 acc[4][4] = {};            // [m = MH*2+fm][n = NH*2+fn], static idx
    bf16x8 aU[2][2], bE[2][2], bO[2][2];

#define LDA(BUF, MH) do { \
    _Pragma("unroll") \
    for (int fm = 0; fm < 2; ++fm) { \
        const int row = wm * 64 + (MH) * 32 + fm * 16 + c16; \
        _Pragma("unroll") \
        for (int ks = 0; ks < 2; ++ks) \
            aU[fm][ks] = *(const bf16x8*)&As[BUF][row * 64 + ((ks * 4 + quad) ^ sw) * 8]; \
    } \
} while (0)
#define LDB(BUF, NH, DST) do { \
    _Pragma("unroll") \
    for (int fn = 0; fn < 2; ++fn) { \
        const int col = wn * 64 + (NH) * 32 + fn * 16 + c16; \
        _Pragma("unroll") \
        for (int ks = 0; ks < 2; ++ks) \
            DST[fn][ks] = *(const bf16x8*)&Bs[BUF][col * 64 + ((ks * 4 + quad) ^ sw) * 8]; \
    } \
} while (0)
#define MM(MB, NB, BM_) do { \
    _Pragma("unroll") \
    for (int fm = 0; fm < 2; ++fm) \
        _Pragma("unroll") \
        for (int fn = 0; fn < 2; ++fn) \
            _Pragma("unroll") \
            for (int ks = 0; ks < 2; ++ks) \
                acc[(MB) + fm][(NB) + fn] = \
                    __builtin_amdgcn_mfma_f32_16x16x32_bf16(aU[fm][ks], BM_[fn][ks], \
                        acc[(MB) + fm][(NB) + fn], 0, 0, 0); \
} while (0)
#define PH_MID() do { \
    __builtin_amdgcn_s_barrier(); \
    asm volatile("s_waitcnt lgkmcnt(0)" ::: "memory"); \
    __builtin_amdgcn_s_setprio(1); \
} while (0)
#define PH_END(VM) do { \
    __builtin_amdgcn_s_setprio(0); \
    if (VM) asm volatile("s_waitcnt vmcnt(6)" ::: "memory"); \
    __builtin_amdgcn_s_barrier(); \
} while (0)

    // prologue: tile0 (buf0) + tile1 (buf1) staged; wait tile0 (6 outstanding)
    STAGE_B0(0, 0); STAGE_A(0, 0); STAGE_B1(0, 0);
    STAGE_B0(1, 1); STAGE_A(1, 1); STAGE_B1(1, 1);
    asm volatile("s_waitcnt vmcnt(6)" ::: "memory");
    __builtin_amdgcn_s_barrier();

    #pragma unroll 1
    for (int it = 0; it < 8; ++it) {
        const int u = 2 * it;
        const int v2 = (u + 2) & 15, v3 = (u + 3) & 15;
        // ---- tile u (buf0); stage tile u+2 -> buf0 ----
        LDA(0, 0); LDB(0, 0, bE);                     PH_MID(); MM(0, 0, bE); PH_END(0);
        LDB(0, 1, bO);            STAGE_B0(0, v2);    PH_MID(); MM(0, 2, bO); PH_END(0);
        LDA(0, 1);                STAGE_B1(0, v2);    PH_MID(); MM(2, 2, bO); PH_END(0);
        /* no ds_reads */         STAGE_A(0, v2);     PH_MID(); MM(2, 0, bE); PH_END(1);
        // ---- tile u+1 (buf1); stage tile u+3 -> buf1 ----
        LDA(1, 0); LDB(1, 0, bE);                     PH_MID(); MM(0, 0, bE); PH_END(0);
        LDB(1, 1, bO);            STAGE_B0(1, v3);    PH_MID(); MM(0, 2, bO); PH_END(0);
        LDA(1, 1);                STAGE_B1(1, v3);    PH_MID(); MM(2, 2, bO); PH_END(0);
        /* no ds_reads */         STAGE_A(1, v3);     PH_MID(); MM(2, 0, bE); PH_END(1);
    }

    asm volatile("s_waitcnt vmcnt(0)" ::: "memory");

    const int rb0 = rowblk + wm * 64 + quad * 4;
    const int cb0 = wn * 64 + c16;
    if (mode == 0) {
        const int z = colblk >> 10;
        const int cm = colblk & 1023;
        const float* bias = (z == 0) ? b0 : (z == 1) ? b1 : b2;
        if (z == 2) {
            short* Vt = (short*)C2;
            #pragma unroll
            for (int m = 0; m < 4; ++m) {
                const int row = rb0 + (m >> 1) * 32 + (m & 1) * 16;
                const int b = row >> 11, s = row & 2047;
                #pragma unroll
                for (int n = 0; n < 4; ++n) {
                    const int cv = cm + cb0 + (n >> 1) * 32 + (n & 1) * 16;
                    const int head = cv >> 6, d = cv & 63;
                    const float bv = bias[cv];
                    u32x2 o = { pkbf(acc[m][n][0] + bv, acc[m][n][1] + bv),
                                pkbf(acc[m][n][2] + bv, acc[m][n][3] + bv) };
                    *(u32x2*)&Vt[((size_t)(b * NHEADS + head) * HDIM + d) * SEQ + s] = o;
                }
            }
        } else {
            short* Cq = (short*)((z == 0) ? C0 : C1);
            const float bsc = (z == 0) ? SL2E : 1.0f;
            #pragma unroll
            for (int m = 0; m < 4; ++m) {
                const int row = rb0 + (m >> 1) * 32 + (m & 1) * 16;
                #pragma unroll
                for (int n = 0; n < 4; ++n) {
                    const int col = cm + cb0 + (n >> 1) * 32 + (n & 1) * 16;
                    const float bv = bias[col] * bsc;
                    #pragma unroll
                    for (int r = 0; r < 4; ++r)
                        Cq[(size_t)(row + r) * EMBED + col] = f2bf(acc[m][n][r] + bv);
                }
            }
        }
    } else {
        float* Co = (float*)C0;
        #pragma unroll
        for (int m = 0; m < 4; ++m) {
            const int row = rb0 + (m >> 1) * 32 + (m & 1) * 16;
            #pragma unroll
            for (int n = 0; n < 4; ++n) {
                const int col = colblk + cb0 + (n >> 1) * 32 + (n & 1) * 16;
                const float bv = b0[col];
                #pragma unroll
                for (int r = 0; r < 4; ++r)
                    Co[(size_t)(row + r) * EMBED + col] = acc[m][n][r] + bv;
            }
        }
    }
#undef PH_END
#undef PH_MID
#undef MM
#undef LDB
#undef LDA
#undef STAGE_B1
#undef STAGE_B0
#undef STAGE_A
}

// ---------- MFMA flash attention v4 (R14): softmax/QK software pipeline ----
// R12/R13 showed staging latency is NOT the stall (dbuf + L2-resident K/V:
// FETCH 139->24.6MB, dur flat; MfmaUtil 33%, VALUBusy 46%, HBM 6% -> neither
// pipe saturated = dependency-bound on the serial chain QK(complete)->exp->
// pack->PV).  Fix (T15-class, one-tile shift): iteration t issues QK(t+1)
// MFMAs FIRST (K(t+1) already in LDS), then exp/pack(t) (operands ready from
// last iter) runs in the MFMA shadow, then PV(t).  Two live st arrays
// (stA/stB, named - rule #20), manual unroll-2 for buffer parity.
// Staging: body t stages K(t+2)->kb[t&1] (K(t) last read by QK(t) issued
// iter t-1, reads complete before the iter t-1 barrier) and V(t+1)->
// vb[(t+1)&1] (V(t-1) last read by PV(t-1) iter t-1).  One extra barrier
// after the prologue QK(0) protects kb0 from body-0's K(2) DMA.
// One vmcnt(0)+s_barrier per tile; T5 setprio; T1 XCD swizzle.
__global__ __launch_bounds__(256, 3) void attn_mfma(const short* __restrict__ Qb,
                                                    const short* __restrict__ Kb,
                                                    const short* __restrict__ Vt,
                                                    short* __restrict__ Ob) {
    __shared__ short SH[16384];      // kb[2] @ 0/4096, vb[2] @ 8192/12288 (shorts)
    const int tid = threadIdx.x;
    const int wave = tid >> 6, lane = tid & 63;
    const int l31 = lane & 31, h = lane >> 5;
    const int swz = l31 & 7;
    // T1 swizzle: grid (16 qb, 64 bh) = 1024 blocks
    const int hid = blockIdx.y * 16 + blockIdx.x;
    const int tle = (hid & 7) * 128 + (hid >> 3);
    const int qb = tle & 15, bh = tle >> 4;
    const int b = bh >> 4, hd = bh & 15;
    const size_t base = (size_t)b * SEQ * EMBED + (size_t)hd * HDIM;
    const size_t vbase = (size_t)bh * HDIM * SEQ;
    const int q0 = qb * 128;

    // Q B-frags for the whole kernel: n=q=l31, k(d) = ks*16 + h*8 + j
    bf16x8 qf[4];
    #pragma unroll
    for (int ks = 0; ks < 4; ++ks)
        qf[ks] = *(const bf16x8*)&Qb[base + (size_t)(q0 + wave * 32 + l31) * EMBED + ks * 16 + h * 8];

    // hoisted staging pointers (advance by constant per staged tile)
    const short* kp[2];
    const short* vp[2];
    int ldofs[2];
    #pragma unroll
    for (int it = 0; it < 2; ++it) {
        int ci = (it * 4 + wave) * 64 + lane;
        int row = ci >> 3, g = (ci & 7) ^ (row & 7);
        kp[it] = Kb + base + (size_t)row * EMBED + g * 8;
        vp[it] = Vt + vbase + (size_t)row * SEQ + g * 8;
        ldofs[it] = (it * 4 + wave) * 512;          // wave-uniform LDS base
    }

#define STAGE_K(J) do { \
    async16(kp[0], &SH[(J) * 4096 + ldofs[0]]); \
    async16(kp[1], &SH[(J) * 4096 + ldofs[1]]); \
    kp[0] += 64 * EMBED; kp[1] += 64 * EMBED; \
} while (0)
#define STAGE_V(J) do { \
    async16(vp[0], &SH[8192 + (J) * 4096 + ldofs[0]]); \
    async16(vp[1], &SH[8192 + (J) * 4096 + ldofs[1]]); \
    vp[0] += 64; vp[1] += 64; \
} while (0)
#define QK_INTO(ST, J) do { \
    _Pragma("unroll") \
    for (int _z = 0; _z < 16; ++_z) { ST[0][_z] = 0.0f; ST[1][_z] = 0.0f; } \
    __builtin_amdgcn_s_setprio(1); \
    _Pragma("unroll") \
    for (int nt = 0; nt < 2; ++nt) \
        _Pragma("unroll") \
        for (int ks = 0; ks < 4; ++ks) { \
            bf16x8 ak = *(const bf16x8*)&SH[(J) * 4096 + (nt * 32 + l31) * 64 + ((ks * 2 + h) ^ swz) * 8]; \
            ST[nt] = __builtin_amdgcn_mfma_f32_32x32x16_bf16(ak, qf[ks], ST[nt], 0, 0, 0); \
        } \
    __builtin_amdgcn_s_setprio(0); \
} while (0)

    f32x16 O[2] = {};
    f32x16 stA[2], stB[2];
    f32x2 ls = {0.0f, 0.0f};

    // prologue: stage K(0)->kb0, V(0)->vb0, K(1)->kb1; then QK(0)->stA
    STAGE_K(0); STAGE_V(0); STAGE_K(1);
    asm volatile("s_waitcnt vmcnt(0)" ::: "memory");
    __builtin_amdgcn_s_barrier();
    QK_INTO(stA, 0);
    __builtin_amdgcn_s_barrier();   // all waves' kb0 reads done before K(2) DMA

// body for tile t: CUR = t&1, NXT = (t+1)&1.  DO_K: stage K(t+2)->kb[CUR];
// DO_V: stage V(t+1)->vb[NXT]; DO_QK: QK(t+1)->STN from kb[NXT].
// Then exp/pack(t) from STC (MFMA-shadowed), PV(t) from vb[CUR].
#define ATT_BODY(CUR, NXT, STC, STN, DO_K, DO_V, DO_QK) do { \
    if (DO_K) STAGE_K(CUR); \
    if (DO_V) STAGE_V(NXT); \
    if (DO_QK) QK_INTO(STN, NXT); \
    u32 pk[2][8]; \
    _Pragma("unroll") \
    for (int nt = 0; nt < 2; ++nt) \
        _Pragma("unroll") \
        for (int i = 0; i < 8; ++i) { \
            float e0 = fexp2(STC[nt][2 * i]), e1 = fexp2(STC[nt][2 * i + 1]); \
            f32x2 e = { e0, e1 }; \
            ls += e; \
            pk[nt][i] = pkbf(e0, e1); \
        } \
    __builtin_amdgcn_s_setprio(1); \
    _Pragma("unroll") \
    for (int ks = 0; ks < 4; ++ks) { \
        const int nt = ks >> 1, bs = (ks & 1) * 4; \
        u32x4 fr; \
        i32x2 sA = __builtin_amdgcn_permlane32_swap((int)pk[nt][bs + 0], (int)pk[nt][bs + 2], false, false); \
        i32x2 sB = __builtin_amdgcn_permlane32_swap((int)pk[nt][bs + 1], (int)pk[nt][bs + 3], false, false); \
        fr.x = (u32)sA.x; fr.y = (u32)sB.x; fr.z = (u32)sA.y; fr.w = (u32)sB.y; \
        bf16x8 pf = __builtin_bit_cast(bf16x8, fr); \
        _Pragma("unroll") \
        for (int mt = 0; mt < 2; ++mt) { \
            bf16x8 vf = *(const bf16x8*)&SH[8192 + (CUR) * 4096 + (mt * 32 + l31) * 64 + ((ks * 2 + h) ^ swz) * 8]; \
            O[mt] = __builtin_amdgcn_mfma_f32_32x32x16_bf16(vf, pf, O[mt], 0, 0, 0); \
        } \
    } \
    __builtin_amdgcn_s_setprio(0); \
    asm volatile("s_waitcnt vmcnt(0)" ::: "memory"); \
    __builtin_amdgcn_s_barrier(); \
} while (0)

    // tiles 0..29 in pairs (all guards true); tail peeled: 30 (no K-stage),
    // 31 (no stages, no QK - exp/PV only)
    #pragma unroll 1
    for (int t = 0; t < 30; t += 2) {
        ATT_BODY(0, 1, stA, stB, 1, 1, 1);
        ATT_BODY(1, 0, stB, stA, 1, 1, 1);
    }
    ATT_BODY(0, 1, stA, stB, 0, 1, 1);   // t=30
    ATT_BODY(1, 0, stB, stA, 0, 0, 0);   // t=31

#undef ATT_BODY
#undef QK_INTO
#undef STAGE_V
#undef STAGE_K

    // finalize: partner lane holds the other half of this q's key-sum
    float lsum = ls.x + ls.y;
    lsum += __shfl_xor(lsum, 32);
    float inv = 1.0f / lsum;

    // O^T[d][q]: col=q=l31, d = mt*32 + (reg&3) + 8*(reg>>2) + 4h.
    // Write bf16 to LDS (XOR-swizzled 8B units), then read rows -> coalesced.
    const int wbase = wave * 2048;
    #pragma unroll
    for (int mt = 0; mt < 2; ++mt)
        #pragma unroll
        for (int m = 0; m < 4; ++m) {
            u32x2 wv;
            wv.x = pkbf(O[mt][4 * m + 0] * inv, O[mt][4 * m + 1] * inv);
            wv.y = pkbf(O[mt][4 * m + 2] * inv, O[mt][4 * m + 3] * inv);
            int u = mt * 8 + 2 * m + h;               // 8B unit index (d = u*4)
            int su = u ^ ((l31 & 7) << 1);
            *(u32x2*)&SH[wbase + l31 * 64 + su * 4] = wv;
        }
    __syncthreads();
    // full tile = 1024 x 16B chunks (4 waves x 32 q x 8 d-chunks)
    #pragma unroll
    for (int p = 0; p < 4; ++p) {
        int ci = p * 256 + tid;
        int wq = ci >> 8, rem = ci & 255;
        int r = rem >> 3, cch = rem & 7;
        int su = (2 * cch) ^ ((r & 7) << 1);
        bf16x8 val = *(const bf16x8*)&SH[wq * 2048 + r * 64 + su * 4];
        *(bf16x8*)&Ob[base + (size_t)(q0 + wq * 32 + r) * EMBED + cch * 8] = val;
    }
}

extern "C" void kernel_launch(void* const* d_in, const int* in_sizes, int n_in,
                              void* d_out, int out_size, void* d_ws, size_t ws_size,
                              hipStream_t stream)
{
    const float* X  = (const float*)d_in[0];
    const float* Wq = (const float*)d_in[1];
    const float* bq = (const float*)d_in[2];
    const float* Wk = (const float*)d_in[3];
    const float* bk = (const float*)d_in[4];
    const float* Wv = (const float*)d_in[5];
    const float* bv = (const float*)d_in[6];
    const float* Wo = (const float*)d_in[7];
    const float* bo = (const float*)d_in[8];
    float* out = (float*)d_out;

    const size_t NE = (size_t)ROWS * EMBED;       // 8M elements
    short* Xbf = (short*)d_ws;                    // 16 MB
    short* Qb  = Xbf + NE;                        // 16 MB (also attention O)
    short* Kb  = Qb + NE;                         // 16 MB
    short* Vtb = Kb + NE;                         // 16 MB  [bh][d][s]
    short* WqT = Vtb + NE;                        // 2 MB each; WqT/WkT/WvT are
    short* WkT = WqT + (size_t)EMBED * EMBED;     //   CONTIGUOUS = combined
    short* WvT = WkT + (size_t)EMBED * EMBED;     //   Wqkv^T [3072][1024]
    short* WoT = WvT + (size_t)EMBED * EMBED;     // total 72 MB

    convert_f32_bf16<<<(ROWS * EMBED) / 1024, 256, 0, stream>>>(X, Xbf);
    dim3 gw(16, 16, 4);
    transpose_w4<<<gw, 256, 0, stream>>>(Wq, Wk, Wv, Wo, WqT, WkT, WvT, WoT);

    // combined QKV: grid (3072/256, 8192/128) = 768 blocks = 3 exact rounds
    dim3 gq(12, 64, 1);
    gemm_p128<<<gq, 512, 0, stream>>>(Xbf, WqT, bq, bk, bv, Qb, Kb, Vtb, 0);

    dim3 gt(SEQ / 128, BATCH * NHEADS);           // (16, 64)
    attn_mfma<<<gt, 256, 0, stream>>>(Qb, Kb, Vtb, Qb);   // O aliases Qb

    // out-proj: grid (1024/256, 8192/128) = 256 blocks = 1 exact round
    dim3 gg(4, 64, 1);
    gemm_p128<<<gg, 512, 0, stream>>>(Qb, WoT, bo, bo, bo, out, out, out, 1);
}

// Round 7
// 259.375 us; speedup vs baseline: 1.0747x; 1.0411x over previous
//
#include <hip/hip_runtime.h>
#include <hip/hip_bf16.h>

#define EMBED 1024
#define NHEADS 16
#define HDIM 64
#define SEQ 2048
#define BATCH 4
#define ROWS (BATCH * SEQ) /* 8192 */

typedef __attribute__((ext_vector_type(8))) short bf16x8;   // 8 bf16 = 4 VGPRs
typedef __attribute__((ext_vector_type(4))) float f32x4;
typedef __attribute__((ext_vector_type(2))) float f32x2;
typedef __attribute__((ext_vector_type(16))) float f32x16;
typedef __attribute__((ext_vector_type(4))) unsigned int u32x4;
typedef __attribute__((ext_vector_type(2))) unsigned int u32x2;
typedef __attribute__((ext_vector_type(2))) int i32x2;
typedef unsigned int u32;

#define SL2E 0.18033688011112042f  /* 0.125 * log2(e) */

__device__ __forceinline__ short f2bf(float f) {            // RTNA fp32->bf16 (2 ops)
    u32 u = __builtin_bit_cast(u32, f) + 0x8000u;
    return (short)(u >> 16);
}

__device__ __forceinline__ u32 pkbf(float a, float b) {     // {bf16(a)|bf16(b)<<16}, 3 ops
    u32 ua = __builtin_bit_cast(u32, a) + 0x8000u;
    u32 ub = __builtin_bit_cast(u32, b) + 0x8000u;
    return __builtin_amdgcn_perm(ua, ub, 0x03020706u);      // v_perm_b32: {a.hi16, b.hi16}
}

__device__ __forceinline__ float fexp2(float x) {
#if __has_builtin(__builtin_amdgcn_exp2f)
    return __builtin_amdgcn_exp2f(x);                       // bare v_exp_f32
#else
    return exp2f(x);
#endif
}

__device__ __forceinline__ void async16(const void* g, void* l) {
    __builtin_amdgcn_global_load_lds((const __attribute__((address_space(1))) u32*)g,
                                     (__attribute__((address_space(3))) u32*)l, 16, 0, 0);
}

// ---------- fp32 -> bf16 elementwise (X) ----------
__global__ __launch_bounds__(256) void convert_f32_bf16(const float* __restrict__ in,
                                                        short* __restrict__ out) {
    int i = (blockIdx.x * 256 + threadIdx.x) * 4;
    float4 v = *(const float4*)&in[i];
    u32x2 o = { pkbf(v.x, v.y), pkbf(v.z, v.w) };
    *(u32x2*)&out[i] = o;
}

// ---------- W[K][N] fp32 -> WT[N][K] bf16; z==0 (Wq) pre-scaled by SL2E ----------
__global__ __launch_bounds__(256) void transpose_w4(const float* __restrict__ W0,
                                                    const float* __restrict__ W1,
                                                    const float* __restrict__ W2,
                                                    const float* __restrict__ W3,
                                                    short* __restrict__ T0,
                                                    short* __restrict__ T1,
                                                    short* __restrict__ T2,
                                                    short* __restrict__ T3) {
    const int z = blockIdx.z;
    const float* W = (z == 0) ? W0 : (z == 1) ? W1 : (z == 2) ? W2 : W3;
    short* WT = (z == 0) ? T0 : (z == 1) ? T1 : (z == 2) ? T2 : T3;
    const float sc = (z == 0) ? SL2E : 1.0f;
    __shared__ float T[64][65];
    const int k0 = blockIdx.y * 64, n0 = blockIdx.x * 64;
    const int rr = threadIdx.x >> 4, cc = (threadIdx.x & 15) * 4;
    #pragma unroll
    for (int p = 0; p < 4; ++p) {
        int r = p * 16 + rr;
        float4 v = *(const float4*)&W[(size_t)(k0 + r) * EMBED + n0 + cc];
        T[r][cc] = v.x * sc; T[r][cc + 1] = v.y * sc; T[r][cc + 2] = v.z * sc; T[r][cc + 3] = v.w * sc;
    }
    __syncthreads();
    #pragma unroll
    for (int p = 0; p < 4; ++p) {
        int r = p * 16 + rr;  // n offset
        u32x2 o = { pkbf(T[cc][r], T[cc + 1][r]), pkbf(T[cc + 2][r], T[cc + 3][r]) };
        *(u32x2*)&WT[(size_t)(n0 + r) * EMBED + k0 + cc] = o;
    }
}

// ============================================================================
// R13 GEMM (unchanged — control): 128x256 8-phase register-reuse schedule,
// BK=64, 8 waves, LDS 96 KiB, T1 XCD swizzle, counted vmcnt(6).
// ============================================================================
__global__ __launch_bounds__(512, 2) void gemm_p128(const short* __restrict__ A,
                                                    const short* __restrict__ BT,
                                                    const float* __restrict__ b0,
                                                    const float* __restrict__ b1,
                                                    const float* __restrict__ b2,
                                                    void* __restrict__ C0,
                                                    void* __restrict__ C1,
                                                    void* __restrict__ C2,
                                                    int mode) {
    __shared__ short As[2][8192];    // [buf][128 rows][64 k], 16B chunks XOR-swizzled
    __shared__ short Bs[2][16384];   // [buf][256 cols][64 k]
    const int tid = threadIdx.x;
    const int lane = tid & 63;
    const int wid = tid >> 6;
    const int c16 = lane & 15, quad = lane >> 4, sw = c16 & 7;
    const int wm = wid >> 2, wn = wid & 3;            // 2M x 4N wave grid
    const int gx = gridDim.x;
    const int hid = blockIdx.y * gx + blockIdx.x;
    const int cpx = (gx * gridDim.y) >> 3;
    const int tle = (hid & 7) * cpx + (hid >> 3);
    const int bx = tle % gx, by = tle / gx;
    const int rowblk = by * 128, colblk = bx * 256;

    const int r0 = tid >> 3;                          // 0..63
    const int g0 = (tid & 7) ^ (r0 & 7);
    const short* aS0 = A + (size_t)(rowblk + r0) * EMBED + g0 * 8;
    const short* bS0 = BT + (size_t)(colblk + r0) * EMBED + g0 * 8;

#define STAGE_A(SBUF, V) do { \
    const short* _s = aS0 + (V) * 64; \
    async16(_s,         &As[SBUF][tid * 8]); \
    async16(_s + 65536, &As[SBUF][tid * 8 + 4096]); \
} while (0)
#define STAGE_B0(SBUF, V) do { \
    const short* _s = bS0 + (V) * 64; \
    async16(_s,         &Bs[SBUF][tid * 8]); \
    async16(_s + 65536, &Bs[SBUF][tid * 8 + 4096]); \
} while (0)
#define STAGE_B1(SBUF, V) do { \
    const short* _s = bS0 + 131072 + (V) * 64; \
    async16(_s,         &Bs[SBUF][tid * 8 + 8192]); \
    async16(_s + 65536, &Bs[SBUF][tid * 8 + 12288]); \
} while (0)

    f32x4 acc[4][4] = {};            // [m = MH*2+fm][n = NH*2+fn], static idx
    bf16x8 aU[2][2], bE[2][2], bO[2][2];

#define LDA(BUF, MH) do { \
    _Pragma("unroll") \
    for (int fm = 0; fm < 2; ++fm) { \
        const int row = wm * 64 + (MH) * 32 + fm * 16 + c16; \
        _Pragma("unroll") \
        for (int ks = 0; ks < 2; ++ks) \
            aU[fm][ks] = *(const bf16x8*)&As[BUF][row * 64 + ((ks * 4 + quad) ^ sw) * 8]; \
    } \
} while (0)
#define LDB(BUF, NH, DST) do { \
    _Pragma("unroll") \
    for (int fn = 0; fn < 2; ++fn) { \
        const int col = wn * 64 + (NH) * 32 + fn * 16 + c16; \
        _Pragma("unroll") \
        for (int ks = 0; ks < 2; ++ks) \
            DST[fn][ks] = *(const bf16x8*)&Bs[BUF][col * 64 + ((ks * 4 + quad) ^ sw) * 8]; \
    } \
} while (0)
#define MM(MB, NB, BM_) do { \
    _Pragma("unroll") \
    for (int fm = 0; fm < 2; ++fm) \
        _Pragma("unroll") \
        for (int fn = 0; fn < 2; ++fn) \
            _Pragma("unroll") \
            for (int ks = 0; ks < 2; ++ks) \
                acc[(MB) + fm][(NB) + fn] = \
                    __builtin_amdgcn_mfma_f32_16x16x32_bf16(aU[fm][ks], BM_[fn][ks], \
                        acc[(MB) + fm][(NB) + fn], 0, 0, 0); \
} while (0)
#define PH_MID() do { \
    __builtin_amdgcn_s_barrier(); \
    asm volatile("s_waitcnt lgkmcnt(0)" ::: "memory"); \
    __builtin_amdgcn_s_setprio(1); \
} while (0)
#define PH_END(VM) do { \
    __builtin_amdgcn_s_setprio(0); \
    if (VM) asm volatile("s_waitcnt vmcnt(6)" ::: "memory"); \
    __builtin_amdgcn_s_barrier(); \
} while (0)

    // prologue: tile0 (buf0) + tile1 (buf1) staged; wait tile0 (6 outstanding)
    STAGE_B0(0, 0); STAGE_A(0, 0); STAGE_B1(0, 0);
    STAGE_B0(1, 1); STAGE_A(1, 1); STAGE_B1(1, 1);
    asm volatile("s_waitcnt vmcnt(6)" ::: "memory");
    __builtin_amdgcn_s_barrier();

    #pragma unroll 1
    for (int it = 0; it < 8; ++it) {
        const int u = 2 * it;
        const int v2 = (u + 2) & 15, v3 = (u + 3) & 15;
        // ---- tile u (buf0); stage tile u+2 -> buf0 ----
        LDA(0, 0); LDB(0, 0, bE);                     PH_MID(); MM(0, 0, bE); PH_END(0);
        LDB(0, 1, bO);            STAGE_B0(0, v2);    PH_MID(); MM(0, 2, bO); PH_END(0);
        LDA(0, 1);                STAGE_B1(0, v2);    PH_MID(); MM(2, 2, bO); PH_END(0);
        /* no ds_reads */         STAGE_A(0, v2);     PH_MID(); MM(2, 0, bE); PH_END(1);
        // ---- tile u+1 (buf1); stage tile u+3 -> buf1 ----
        LDA(1, 0); LDB(1, 0, bE);                     PH_MID(); MM(0, 0, bE); PH_END(0);
        LDB(1, 1, bO);            STAGE_B0(1, v3);    PH_MID(); MM(0, 2, bO); PH_END(0);
        LDA(1, 1);                STAGE_B1(1, v3);    PH_MID(); MM(2, 2, bO); PH_END(0);
        /* no ds_reads */         STAGE_A(1, v3);     PH_MID(); MM(2, 0, bE); PH_END(1);
    }

    asm volatile("s_waitcnt vmcnt(0)" ::: "memory");

    const int rb0 = rowblk + wm * 64 + quad * 4;
    const int cb0 = wn * 64 + c16;
    if (mode == 0) {
        const int z = colblk >> 10;
        const int cm = colblk & 1023;
        const float* bias = (z == 0) ? b0 : (z == 1) ? b1 : b2;
        if (z == 2) {
            short* Vt = (short*)C2;
            #pragma unroll
            for (int m = 0; m < 4; ++m) {
                const int row = rb0 + (m >> 1) * 32 + (m & 1) * 16;
                const int b = row >> 11, s = row & 2047;
                #pragma unroll
                for (int n = 0; n < 4; ++n) {
                    const int cv = cm + cb0 + (n >> 1) * 32 + (n & 1) * 16;
                    const int head = cv >> 6, d = cv & 63;
                    const float bv = bias[cv];
                    u32x2 o = { pkbf(acc[m][n][0] + bv, acc[m][n][1] + bv),
                                pkbf(acc[m][n][2] + bv, acc[m][n][3] + bv) };
                    *(u32x2*)&Vt[((size_t)(b * NHEADS + head) * HDIM + d) * SEQ + s] = o;
                }
            }
        } else {
            short* Cq = (short*)((z == 0) ? C0 : C1);
            const float bsc = (z == 0) ? SL2E : 1.0f;
            #pragma unroll
            for (int m = 0; m < 4; ++m) {
                const int row = rb0 + (m >> 1) * 32 + (m & 1) * 16;
                #pragma unroll
                for (int n = 0; n < 4; ++n) {
                    const int col = cm + cb0 + (n >> 1) * 32 + (n & 1) * 16;
                    const float bv = bias[col] * bsc;
                    #pragma unroll
                    for (int r = 0; r < 4; ++r)
                        Cq[(size_t)(row + r) * EMBED + col] = f2bf(acc[m][n][r] + bv);
                }
            }
        }
    } else {
        float* Co = (float*)C0;
        #pragma unroll
        for (int m = 0; m < 4; ++m) {
            const int row = rb0 + (m >> 1) * 32 + (m & 1) * 16;
            #pragma unroll
            for (int n = 0; n < 4; ++n) {
                const int col = colblk + cb0 + (n >> 1) * 32 + (n & 1) * 16;
                const float bv = b0[col];
                #pragma unroll
                for (int r = 0; r < 4; ++r)
                    Co[(size_t)(row + r) * EMBED + col] = acc[m][n][r] + bv;
            }
        }
    }
#undef PH_END
#undef PH_MID
#undef MM
#undef LDB
#undef LDA
#undef STAGE_B1
#undef STAGE_B0
#undef STAGE_A
}

// ---------- MFMA flash attention v5 (R16 = R15 theory, compile-fixed) ----
// Diagnosis (R12-R14): OccupancyPercent pinned at 24% = 3 blocks/CU resident
// over a 1024-block grid -> 768-block round 1 + 256-block tail at 1/3
// capacity.  Limiter is the unified VGPR+AGPR budget (~132-160: O[2]=32 +
// st-state f32x16s on top of ~70 VGPR) -> 3 waves/SIMD band.
// Fix: (a) drop the R14 QK-ahead (null, m253) -32 regs; (b) split each
// K/V-tile into per-nt halves (QK(nt) -> exp/pack(nt) -> PV(2nt,2nt+1)) so
// S-state liveness is ONE f32x16 (16 regs) and pk is 8 regs; (c)
// __launch_bounds__(256,4) -> allocator targets <=128 total -> 4 blocks/CU
// -> 1024 blocks = exactly one full round, no tail.  ILP lost to the tighter
// QK->exp chain is repaid by 2x TLP (m114: wave-level overlap).
// Keeps: K/V dbuf, one vmcnt(0)+s_barrier per tile, T5 setprio, T1 swizzle.
__global__ __launch_bounds__(256, 4) void attn_mfma(const short* __restrict__ Qb,
                                                    const short* __restrict__ Kb,
                                                    const short* __restrict__ Vt,
                                                    short* __restrict__ Ob) {
    __shared__ short SH[16384];      // kb[2] @ 0/4096, vb[2] @ 8192/12288 (shorts)
    const int tid = threadIdx.x;
    const int wave = tid >> 6, lane = tid & 63;
    const int l31 = lane & 31, h = lane >> 5;
    const int swz = l31 & 7;
    // T1 swizzle: grid (16 qb, 64 bh) = 1024 blocks
    const int hid = blockIdx.y * 16 + blockIdx.x;
    const int tle = (hid & 7) * 128 + (hid >> 3);
    const int qb = tle & 15, bh = tle >> 4;
    const int b = bh >> 4, hd = bh & 15;
    const size_t base = (size_t)b * SEQ * EMBED + (size_t)hd * HDIM;
    const size_t vbase = (size_t)bh * HDIM * SEQ;
    const int q0 = qb * 128;

    // Q B-frags for the whole kernel: n=q=l31, k(d) = ks*16 + h*8 + j
    bf16x8 qf[4];
    #pragma unroll
    for (int ks = 0; ks < 4; ++ks)
        qf[ks] = *(const bf16x8*)&Qb[base + (size_t)(q0 + wave * 32 + l31) * EMBED + ks * 16 + h * 8];

    // hoisted staging pointers (advance by constant per staged tile)
    const short* kp[2];
    const short* vp[2];
    int ldofs[2];
    #pragma unroll
    for (int it = 0; it < 2; ++it) {
        int ci = (it * 4 + wave) * 64 + lane;
        int row = ci >> 3, g = (ci & 7) ^ (row & 7);
        kp[it] = Kb + base + (size_t)row * EMBED + g * 8;
        vp[it] = Vt + vbase + (size_t)row * SEQ + g * 8;
        ldofs[it] = (it * 4 + wave) * 512;          // wave-uniform LDS base
    }

#define STAGE_KV(J) do { \
    async16(kp[0], &SH[(J) * 4096 + ldofs[0]]); \
    async16(kp[1], &SH[(J) * 4096 + ldofs[1]]); \
    async16(vp[0], &SH[8192 + (J) * 4096 + ldofs[0]]); \
    async16(vp[1], &SH[8192 + (J) * 4096 + ldofs[1]]); \
    kp[0] += 64 * EMBED; kp[1] += 64 * EMBED; \
    vp[0] += 64; vp[1] += 64; \
} while (0)

    f32x16 O[2] = {};
    f32x2 ls = {0.0f, 0.0f};

    // prologue: stage tile 0 into buf0
    STAGE_KV(0);
    asm volatile("s_waitcnt vmcnt(0)" ::: "memory");
    __builtin_amdgcn_s_barrier();

// One K/V tile from buffer CUR; optionally stage tile t+1 into buf NXT first.
// Per-nt half: QK(nt) 4 MFMA -> exp/pack (8 exp-pairs, 8 pk words) ->
// PV steps ks=2nt,2nt+1 (4 MFMA).  S-liveness = one f32x16, pk = 8 regs.
#define ATT_TILE(CUR, NXT, DO_STAGE) do { \
    if (DO_STAGE) STAGE_KV(NXT); \
    _Pragma("unroll") \
    for (int nt = 0; nt < 2; ++nt) { \
        f32x16 st = {0.0f, 0.0f, 0.0f, 0.0f, 0.0f, 0.0f, 0.0f, 0.0f, \
                     0.0f, 0.0f, 0.0f, 0.0f, 0.0f, 0.0f, 0.0f, 0.0f}; \
        __builtin_amdgcn_s_setprio(1); \
        _Pragma("unroll") \
        for (int ks = 0; ks < 4; ++ks) { \
            bf16x8 ak = *(const bf16x8*)&SH[(CUR) * 4096 + (nt * 32 + l31) * 64 + ((ks * 2 + h) ^ swz) * 8]; \
            st = __builtin_amdgcn_mfma_f32_32x32x16_bf16(ak, qf[ks], st, 0, 0, 0); \
        } \
        __builtin_amdgcn_s_setprio(0); \
        u32 pk[8]; \
        _Pragma("unroll") \
        for (int i = 0; i < 8; ++i) { \
            float e0 = fexp2(st[2 * i]), e1 = fexp2(st[2 * i + 1]); \
            f32x2 e = { e0, e1 }; \
            ls += e; \
            pk[i] = pkbf(e0, e1); \
        } \
        __builtin_amdgcn_s_setprio(1); \
        _Pragma("unroll") \
        for (int kk = 0; kk < 2; ++kk) { \
            const int ks = nt * 2 + kk, bs = kk * 4; \
            u32x4 fr; \
            i32x2 sA = __builtin_amdgcn_permlane32_swap((int)pk[bs + 0], (int)pk[bs + 2], false, false); \
            i32x2 sB = __builtin_amdgcn_permlane32_swap((int)pk[bs + 1], (int)pk[bs + 3], false, false); \
            fr.x = (u32)sA.x; fr.y = (u32)sB.x; fr.z = (u32)sA.y; fr.w = (u32)sB.y; \
            bf16x8 pf = __builtin_bit_cast(bf16x8, fr); \
            _Pragma("unroll") \
            for (int mt = 0; mt < 2; ++mt) { \
                bf16x8 vf = *(const bf16x8*)&SH[8192 + (CUR) * 4096 + (mt * 32 + l31) * 64 + ((ks * 2 + h) ^ swz) * 8]; \
                O[mt] = __builtin_amdgcn_mfma_f32_32x32x16_bf16(vf, pf, O[mt], 0, 0, 0); \
            } \
        } \
        __builtin_amdgcn_s_setprio(0); \
    } \
    asm volatile("s_waitcnt vmcnt(0)" ::: "memory"); \
    __builtin_amdgcn_s_barrier(); \
} while (0)

    // tiles 0..30 stage t+1; tile 31 computes only
    #pragma unroll 1
    for (int t = 0; t < 30; t += 2) {
        ATT_TILE(0, 1, 1);
        ATT_TILE(1, 0, 1);
    }
    ATT_TILE(0, 1, 1);   // t=30, stages 31 -> buf1
    ATT_TILE(1, 0, 0);   // t=31

#undef ATT_TILE
#undef STAGE_KV

    // finalize: partner lane holds the other half of this q's key-sum
    float lsum = ls.x + ls.y;
    lsum += __shfl_xor(lsum, 32);
    float inv = 1.0f / lsum;

    // O^T[d][q]: col=q=l31, d = mt*32 + (reg&3) + 8*(reg>>2) + 4h.
    // Write bf16 to LDS (XOR-swizzled 8B units), then read rows -> coalesced.
    const int wbase = wave * 2048;
    #pragma unroll
    for (int mt = 0; mt < 2; ++mt)
        #pragma unroll
        for (int m = 0; m < 4; ++m) {
            u32x2 wv;
            wv.x = pkbf(O[mt][4 * m + 0] * inv, O[mt][4 * m + 1] * inv);
            wv.y = pkbf(O[mt][4 * m + 2] * inv, O[mt][4 * m + 3] * inv);
            int u = mt * 8 + 2 * m + h;               // 8B unit index (d = u*4)
            int su = u ^ ((l31 & 7) << 1);
            *(u32x2*)&SH[wbase + l31 * 64 + su * 4] = wv;
        }
    __syncthreads();
    // full tile = 1024 x 16B chunks (4 waves x 32 q x 8 d-chunks)
    #pragma unroll
    for (int p = 0; p < 4; ++p) {
        int ci = p * 256 + tid;
        int wq = ci >> 8, rem = ci & 255;
        int r = rem >> 3, cch = rem & 7;
        int su = (2 * cch) ^ ((r & 7) << 1);
        bf16x8 val = *(const bf16x8*)&SH[wq * 2048 + r * 64 + su * 4];
        *(bf16x8*)&Ob[base + (size_t)(q0 + wq * 32 + r) * EMBED + cch * 8] = val;
    }
}

extern "C" void kernel_launch(void* const* d_in, const int* in_sizes, int n_in,
                              void* d_out, int out_size, void* d_ws, size_t ws_size,
                              hipStream_t stream)
{
    const float* X  = (const float*)d_in[0];
    const float* Wq = (const float*)d_in[1];
    const float* bq = (const float*)d_in[2];
    const float* Wk = (const float*)d_in[3];
    const float* bk = (const float*)d_in[4];
    const float* Wv = (const float*)d_in[5];
    const float* bv = (const float*)d_in[6];
    const float* Wo = (const float*)d_in[7];
    const float* bo = (const float*)d_in[8];
    float* out = (float*)d_out;

    const size_t NE = (size_t)ROWS * EMBED;       // 8M elements
    short* Xbf = (short*)d_ws;                    // 16 MB
    short* Qb  = Xbf + NE;                        // 16 MB (also attention O)
    short* Kb  = Qb + NE;                         // 16 MB
    short* Vtb = Kb + NE;                         // 16 MB  [bh][d][s]
    short* WqT = Vtb + NE;                        // 2 MB each; WqT/WkT/WvT are
    short* WkT = WqT + (size_t)EMBED * EMBED;     //   CONTIGUOUS = combined
    short* WvT = WkT + (size_t)EMBED * EMBED;     //   Wqkv^T [3072][1024]
    short* WoT = WvT + (size_t)EMBED * EMBED;     // total 72 MB

    convert_f32_bf16<<<(ROWS * EMBED) / 1024, 256, 0, stream>>>(X, Xbf);
    dim3 gw(16, 16, 4);
    transpose_w4<<<gw, 256, 0, stream>>>(Wq, Wk, Wv, Wo, WqT, WkT, WvT, WoT);

    // combined QKV: grid (3072/256, 8192/128) = 768 blocks = 3 exact rounds
    dim3 gq(12, 64, 1);
    gemm_p128<<<gq, 512, 0, stream>>>(Xbf, WqT, bq, bk, bv, Qb, Kb, Vtb, 0);

    dim3 gt(SEQ / 128, BATCH * NHEADS);           // (16, 64)
    attn_mfma<<<gt, 256, 0, stream>>>(Qb, Kb, Vtb, Qb);   // O aliases Qb

    // out-proj: grid (1024/256, 8192/128) = 256 blocks = 1 exact round
    dim3 gg(4, 64, 1);
    gemm_p128<<<gg, 512, 0, stream>>>(Qb, WoT, bo, bo, bo, out, out, out, 1);
}